// Round 11
// baseline (125.712 us; speedup 1.0000x reference)
//
#include <hip/hip_runtime.h>
#include <hip/hip_bf16.h>

#define B_SZ 2
#define S_LEN 2048
#define E_DIM 1024
#define NH 16
#define DH 64
#define M_ROWS (B_SZ * S_LEN) /* 4096 */
#define KVB 64

typedef __attribute__((ext_vector_type(8))) short short8;
typedef __attribute__((ext_vector_type(4))) float floatx4;
typedef __attribute__((ext_vector_type(4))) int intx4;

static __device__ __forceinline__ unsigned short f2bf(float f) {
    __hip_bfloat16 h = __float2bfloat16(f);
    return *reinterpret_cast<unsigned short*>(&h);
}
static __device__ __forceinline__ float bf2f(unsigned short u) {
    unsigned int v = ((unsigned int)u) << 16;
    return __builtin_bit_cast(float, v);
}
static __device__ __forceinline__ unsigned int pack2bf(float lo, float hi) {
    return (unsigned int)f2bf(lo) | ((unsigned int)f2bf(hi) << 16);
}

static __device__ __forceinline__ void gl2lds16(const void* g, void* l) {
    __builtin_amdgcn_global_load_lds((const __attribute__((address_space(1))) void*)g,
                                     (__attribute__((address_space(3))) void*)l, 16, 0, 0);
}

#define WAIT_VM0() asm volatile("s_waitcnt vmcnt(0)" ::: "memory")
#define WAIT_LGKM0() asm volatile("s_waitcnt lgkmcnt(0)" ::: "memory")

// ---------------- prep: fp32->bf16 convert (x) + 4 weight transposes, fused --------
__global__ __launch_bounds__(256) void prep(const float* __restrict__ x,
                                            unsigned short* __restrict__ Xb,
                                            const float* __restrict__ W0,
                                            const float* __restrict__ W1,
                                            const float* __restrict__ W2,
                                            const float* __restrict__ W3,
                                            unsigned short* __restrict__ T0,
                                            unsigned short* __restrict__ T1,
                                            unsigned short* __restrict__ T2,
                                            unsigned short* __restrict__ T3) {
    __shared__ float tile[32][33];
    int bid = blockIdx.x;
    int t = threadIdx.x;
    if (bid < 4096) { // cvt: 4096 blocks x 1024 elems
        int i = (bid * 256 + t) * 4;
        float4 v = *reinterpret_cast<const float4*>(x + i);
        ushort4 o;
        o.x = f2bf(v.x); o.y = f2bf(v.y); o.z = f2bf(v.z); o.w = f2bf(v.w);
        *reinterpret_cast<ushort4*>(Xb + i) = o;
        return;
    }
    int u = bid - 4096;
    int z = u >> 10, rest = u & 1023;
    int bx = (rest & 31) * 32, by = (rest >> 5) * 32;
    const float* W = (z == 0) ? W0 : (z == 1) ? W1 : (z == 2) ? W2 : W3;
    unsigned short* Wt = (z == 0) ? T0 : (z == 1) ? T1 : (z == 2) ? T2 : T3;
    int tx = t & 31, ty = t >> 5; // 32 x 8
#pragma unroll
    for (int i = 0; i < 32; i += 8)
        tile[ty + i][tx] = W[(size_t)(by + ty + i) * E_DIM + bx + tx];
    __syncthreads();
#pragma unroll
    for (int i = 0; i < 32; i += 8)
        Wt[(size_t)(bx + ty + i) * E_DIM + by + tx] = f2bf(tile[tx][ty + i]);
}

// Q scale folds 1/sqrt(D) AND log2(e) so attention can use raw v_exp_f32 (2^x).
#define QSCALE 0.18033688011112042f

// ---------------- fused QKV projection: 8-phase 256x256 schedule --------------------
__global__ __launch_bounds__(512, 2) void gemm_qkv8(const unsigned short* __restrict__ Wcat,
                                                    const unsigned short* __restrict__ Xb,
                                                    const float* __restrict__ bq,
                                                    const float* __restrict__ bk,
                                                    const float* __restrict__ bv,
                                                    unsigned short* __restrict__ Qg,
                                                    unsigned short* __restrict__ Kg,
                                                    unsigned short* __restrict__ Vtg) {
    __shared__ __align__(16) char lds[2][2][32768]; // [buf][A=0/B=1][256 rows x 128B]

    int t = threadIdx.x;
    int b = blockIdx.x;
    int xcd = b & 7, ii = b >> 3;
    int it = (xcd & 3) * 3 + (ii >> 3); // 0..11
    int jt = (xcd >> 2) * 8 + (ii & 7); // 0..15
    int iBase = it << 8, jBase = jt << 8;

    int w = t >> 6, lane = t & 63;
    int lr = lane & 15, lh = lane >> 4;
    int wm = w >> 2, wn = w & 3; // 2m x 4n waves

    int srow = t >> 3;             // 0..63
    int scbx = ((t & 7) << 4) ^ ((srow & 7) << 4);

    const char* Ab = (const char*)Wcat;
    const char* Bb = (const char*)Xb;

    floatx4 acc[8][4];
#pragma unroll
    for (int i = 0; i < 8; i++)
#pragma unroll
        for (int j = 0; j < 4; j++) acc[i][j] = (floatx4){0.f, 0.f, 0.f, 0.f};

    auto stageA = [&](int buf, int kt) {
        int k0b = kt << 7;
#pragma unroll
        for (int c = 0; c < 4; c++)
            gl2lds16(Ab + (size_t)(iBase + c * 64 + srow) * 2048 + k0b + scbx,
                     &lds[buf][0][c * 8192 + t * 16]);
    };
    auto stageB = [&](int buf, int kt) {
        int k0b = kt << 7;
#pragma unroll
        for (int c = 0; c < 4; c++)
            gl2lds16(Bb + (size_t)(jBase + c * 64 + srow) * 2048 + k0b + scbx,
                     &lds[buf][1][c * 8192 + t * 16]);
    };

    short8 af[4][2], bf[4][2];
    auto rdA = [&](int buf, int qm) {
#pragma unroll
        for (int mi = 0; mi < 4; mi++)
#pragma unroll
            for (int ks = 0; ks < 2; ks++) {
                int row = wm * 128 + qm * 64 + mi * 16 + lr;
                af[mi][ks] = *reinterpret_cast<const short8*>(
                    &lds[buf][0][(row * 128 + ks * 64 + lh * 16) ^ ((row & 7) << 4)]);
            }
    };
    auto rdB = [&](int buf, int qn) {
#pragma unroll
        for (int ni = 0; ni < 2; ni++)
#pragma unroll
            for (int ks = 0; ks < 2; ks++) {
                int row = wn * 64 + qn * 32 + ni * 16 + lr;
                bf[qn * 2 + ni][ks] = *reinterpret_cast<const short8*>(
                    &lds[buf][1][(row * 128 + ks * 64 + lh * 16) ^ ((row & 7) << 4)]);
            }
    };
    auto mfma16 = [&](int qm, int qn) {
        __builtin_amdgcn_s_setprio(1);
#pragma unroll
        for (int mi = 0; mi < 4; mi++)
#pragma unroll
            for (int ni = 0; ni < 2; ni++)
#pragma unroll
                for (int ks = 0; ks < 2; ks++)
                    acc[qm * 4 + mi][qn * 2 + ni] = __builtin_amdgcn_mfma_f32_16x16x32_bf16(
                        af[mi][ks], bf[qn * 2 + ni][ks], acc[qm * 4 + mi][qn * 2 + ni], 0, 0, 0);
        __builtin_amdgcn_s_setprio(0);
    };

    const int NT = 16; // K=1024 / 64
    stageA(0, 0);
    stageB(0, 0);
    WAIT_VM0();
    __builtin_amdgcn_s_barrier();

    for (int kt = 0; kt < NT; ++kt) {
        int cur = kt & 1, nxt = cur ^ 1;
        bool pf = (kt + 1 < NT);
        // ---- phase 0: quadrant (0,0); prefetch next A ----
        rdA(cur, 0);
        rdB(cur, 0);
        if (pf) stageA(nxt, kt + 1);
        __builtin_amdgcn_s_barrier();
        WAIT_LGKM0();
        __builtin_amdgcn_sched_barrier(0);
        mfma16(0, 0);
        __builtin_amdgcn_s_barrier();
        // ---- phase 1: quadrant (0,1); prefetch next B ----
        rdB(cur, 1);
        if (pf) stageB(nxt, kt + 1);
        __builtin_amdgcn_s_barrier();
        WAIT_LGKM0();
        __builtin_amdgcn_sched_barrier(0);
        mfma16(0, 1);
        __builtin_amdgcn_s_barrier();
        // ---- phase 2: quadrant (1,0) ----
        rdA(cur, 1);
        __builtin_amdgcn_s_barrier();
        WAIT_LGKM0();
        __builtin_amdgcn_sched_barrier(0);
        mfma16(1, 0);
        __builtin_amdgcn_s_barrier();
        // ---- phase 3: quadrant (1,1); drain prefetch before next-iter reads ----
        if (pf) WAIT_VM0();
        __builtin_amdgcn_s_barrier();
        mfma16(1, 1);
        __builtin_amdgcn_s_barrier();
    }

    // ---------------- epilogue ----------------
    int wsel = iBase >> 10;
    const float* bias = (wsel == 0) ? bq : (wsel == 1) ? bk : bv;
    __syncthreads(); // LDS free for reuse

    if (wsel < 2) {
        unsigned short* O = wsel ? Kg : Qg;
        float scale = wsel ? 1.0f : QSCALE;
#pragma unroll
        for (int mi8 = 0; mi8 < 8; mi8++) {
            int i = iBase + wm * 128 + mi8 * 16 + lh * 4;
            int im = i & 1023;
            int h = im >> 6, d0 = im & 63;
            float4 bs = *reinterpret_cast<const float4*>(&bias[im]);
#pragma unroll
            for (int nf = 0; nf < 4; nf++) {
                int j = jBase + wn * 64 + nf * 16 + lr;
                int b_ = j >> 11, s = j & (S_LEN - 1);
                ushort4 pk;
                pk.x = f2bf((acc[mi8][nf][0] + bs.x) * scale);
                pk.y = f2bf((acc[mi8][nf][1] + bs.y) * scale);
                pk.z = f2bf((acc[mi8][nf][2] + bs.z) * scale);
                pk.w = f2bf((acc[mi8][nf][3] + bs.w) * scale);
                *reinterpret_cast<ushort4*>(
                    &O[((size_t)(b_ * NH + h) * S_LEN + s) * DH + d0]) = pk;
            }
        }
    } else {
        // V: transpose each wave's 128x64 slab through LDS -> [b][h][d][s] coalesced
        char* lw = &lds[0][0][0] + w * 16384;
#pragma unroll
        for (int mi8 = 0; mi8 < 8; mi8++) {
            int i = iBase + wm * 128 + mi8 * 16 + lh * 4;
            float4 bs = *reinterpret_cast<const float4*>(&bias[i & 1023]);
#pragma unroll
            for (int nf = 0; nf < 4; nf++) {
                int jl = nf * 16 + lr;
#pragma unroll
                for (int r = 0; r < 4; r++) {
                    int il = mi8 * 16 + lh * 4 + r;
                    float bb = (r == 0) ? bs.x : (r == 1) ? bs.y : (r == 2) ? bs.z : bs.w;
                    *reinterpret_cast<unsigned short*>(
                        lw + ((il * 128 + jl * 2) ^ ((il & 7) << 4))) =
                        f2bf(acc[mi8][nf][r] + bb);
                }
            }
        }
        __syncthreads();
#pragma unroll
        for (int rep = 0; rep < 16; rep++) {
            int idx = rep * 64 + lane;
            int il = idx >> 3, jb = idx & 7;
            short8 vv = *reinterpret_cast<const short8*>(
                lw + ((il * 128 + jb * 16) ^ ((il & 7) << 4)));
            int i = iBase + wm * 128 + il;
            int im = i & 1023;
            int h = im >> 6, d = im & 63;
            int j = jBase + wn * 64 + jb * 8;
            int b_ = j >> 11, s = j & (S_LEN - 1);
            *reinterpret_cast<short8*>(
                &Vtg[((size_t)(b_ * NH + h) * DH + d) * S_LEN + s]) = vv;
        }
    }
}

// ---------------- output projection (128x64 tiles, 2-phase, fp32 out) ---------------
template <int NI>
static __device__ __forceinline__ void gemm_tile_mainloop(
    const unsigned short* __restrict__ A, const unsigned short* __restrict__ Bt,
    int mBase, int nBase, char* ldsA, char* ldsB, floatx4 (&acc)[4][NI]) {
    const int K = E_DIM;
    int t = threadIdx.x;
    int w = t >> 6, lane = t & 63;
    int lr = lane & 15, lh = lane >> 4;
    int wm = w >> 1, wn = w & 1;
    const char* Ab = (const char*)A;
    const char* Bb = (const char*)Bt;
    int srow = t >> 3;
    int scb = ((t & 7) << 4) ^ ((srow & 7) << 4);

#pragma unroll
    for (int mi = 0; mi < 4; mi++)
#pragma unroll
        for (int ni = 0; ni < NI; ni++) acc[mi][ni] = (floatx4){0.f, 0.f, 0.f, 0.f};

    for (int kt = 0; kt < K / 64; ++kt) {
        int k0 = kt * 64;
#pragma unroll
        for (int i = 0; i < 4; i++)
            gl2lds16(Ab + (size_t)(mBase + i * 32 + srow) * (K * 2) + k0 * 2 + scb,
                     ldsA + i * 4096 + t * 16);
#pragma unroll
        for (int i = 0; i < NI; i++)
            gl2lds16(Bb + (size_t)(nBase + i * 32 + srow) * (K * 2) + k0 * 2 + scb,
                     ldsB + i * 4096 + t * 16);
        __syncthreads();
#pragma unroll
        for (int ks = 0; ks < 2; ks++) {
            short8 af[4], bfr[NI];
#pragma unroll
            for (int mi = 0; mi < 4; mi++) {
                int row = wm * 64 + mi * 16 + lr;
                af[mi] = *reinterpret_cast<const short8*>(
                    ldsA + ((row * 128 + ks * 64 + lh * 16) ^ ((row & 7) << 4)));
            }
#pragma unroll
            for (int ni = 0; ni < NI; ni++) {
                int row = wn * (NI * 16) + ni * 16 + lr;
                bfr[ni] = *reinterpret_cast<const short8*>(
                    ldsB + ((row * 128 + ks * 64 + lh * 16) ^ ((row & 7) << 4)));
            }
#pragma unroll
            for (int mi = 0; mi < 4; mi++)
#pragma unroll
                for (int ni = 0; ni < NI; ni++)
                    acc[mi][ni] = __builtin_amdgcn_mfma_f32_16x16x32_bf16(af[mi], bfr[ni],
                                                                          acc[mi][ni], 0, 0, 0);
        }
        __syncthreads();
    }
}

__global__ __launch_bounds__(256) void gemm_o(const unsigned short* __restrict__ Og,
                                              const unsigned short* __restrict__ Wot,
                                              const float* __restrict__ bo,
                                              float* __restrict__ out) {
    __shared__ __align__(16) char ldsA[16384];
    __shared__ __align__(16) char ldsB[8192];
    int bid = blockIdx.y * 16 + blockIdx.x;
    int xcd = bid & 7, ii = bid >> 3; // ii in [0,64)
    int xx = ii & 15;
    int yy = (xcd << 2) | (ii >> 4);
    int nBase = xx << 6;
    int mBase = yy << 7;

    floatx4 acc[4][2];
    gemm_tile_mainloop<2>(Og, Wot, mBase, nBase, ldsA, ldsB, acc);

    int w = threadIdx.x >> 6, lane = threadIdx.x & 63;
    int lr = lane & 15, lh = lane >> 4;
    int wm = w >> 1, wn = w & 1;
#pragma unroll
    for (int mi = 0; mi < 4; mi++)
#pragma unroll
        for (int ni = 0; ni < 2; ni++)
#pragma unroll
            for (int r = 0; r < 4; r++) {
                int m = mBase + wm * 64 + mi * 16 + lh * 4 + r;
                int n = nBase + wn * 32 + ni * 16 + lr;
                out[(size_t)m * E_DIM + n] = acc[mi][ni][r] + bo[n];
            }
}

// ---------------- causal flash attention: QB=256/block, swapped QK^T, in-reg P ------
// 4 waves x 64 q-rows (4 m-frags). KV-split chunks of <=8 tiles -> 23 blocks/bh,
// 736 blocks (~2.9/CU, 2 resident via 32KB LDS + VGPR cap). Partials: 672 slots of
// 32KB split across two proven ws regions (448 in Xb-overlay, 224 after Og).
__global__ __launch_bounds__(256, 2) void attn_fwd(const unsigned short* __restrict__ Qg,
                                                   const unsigned short* __restrict__ Kg,
                                                   const unsigned short* __restrict__ Vtg,
                                                   unsigned short* __restrict__ Og,
                                                   unsigned short* __restrict__ OpA,
                                                   unsigned short* __restrict__ OpB,
                                                   float* __restrict__ lpart) {
    __shared__ __align__(16) char kt_lds[2][KVB * 128];
    __shared__ __align__(16) char vt_lds[2][KVB * 128];

    int bid = blockIdx.x;
    int xcd = bid & 7, ii = bid >> 3;  // [0,92)
    int bh = (xcd << 2) + ii / 23;
    int jj = ii % 23;                  // big-qb chunks first
    int qb, ch, c, base;
    if (jj < 5)        { qb = 7; ch = jj;      c = 5; base = 16; }
    else if (jj < 9)   { qb = 6; ch = jj - 5;  c = 4; base = 12; }
    else if (jj < 13)  { qb = 5; ch = jj - 9;  c = 4; base = 8;  }
    else if (jj < 16)  { qb = 4; ch = jj - 13; c = 3; base = 5;  }
    else if (jj < 19)  { qb = 3; ch = jj - 16; c = 3; base = 2;  }
    else if (jj < 21)  { qb = 2; ch = jj - 19; c = 2; base = 0;  }
    else if (jj == 21) { qb = 1; ch = 0;       c = 1; base = 0;  }
    else               { qb = 0; ch = 0;       c = 1; base = 0;  }
    int T = 4 * qb + 4;
    int kt_lo = ch * T / c;
    int kt_hi = (ch + 1) * T / c - 1;
    bool split = (c > 1);

    int w = threadIdx.x >> 6, lane = threadIdx.x & 63;
    int lr = lane & 15, lh = lane >> 4;
    int q0 = qb * 256 + w * 64;

    const char* Kb = (const char*)(Kg + (size_t)bh * S_LEN * DH);
    const char* Vb = (const char*)(Vtg + (size_t)bh * DH * S_LEN);
    const unsigned short* Qb = Qg + (size_t)bh * S_LEN * DH;

    int wi0 = w * 2;
    int srow0 = wi0 * 8 + (lane >> 3);
    int scol = (lane & 7) << 4;

    auto stage = [&](int buf, int kt) { // K + V tiles, 2+2 x 1KB per wave
        int kv0 = kt * KVB;
#pragma unroll
        for (int i = 0; i < 2; ++i) {
            int row = srow0 + i * 8;
            int colb = scol ^ ((row & 7) << 4);
            gl2lds16(Kb + (size_t)(kv0 + row) * 128 + colb,
                     kt_lds[buf] + (wi0 + i) * 1024);
            gl2lds16(Vb + (size_t)row * (S_LEN * 2) + (size_t)kv0 * 2 + colb,
                     vt_lds[buf] + (wi0 + i) * 1024);
        }
    };

    short8 aq[4][2];
#pragma unroll
    for (int m = 0; m < 4; m++)
#pragma unroll
        for (int ks = 0; ks < 2; ks++)
            aq[m][ks] = *reinterpret_cast<const short8*>(
                Qb + (size_t)(q0 + m * 16 + lr) * DH + ks * 32 + lh * 8);

    floatx4 oacc[4][4];
    float lsum[4];
#pragma unroll
    for (int m = 0; m < 4; m++) {
#pragma unroll
        for (int dt = 0; dt < 4; dt++) oacc[m][dt] = (floatx4){0.f, 0.f, 0.f, 0.f};
        lsum[m] = 0.f;
    }

    stage(0, kt_lo);
    __syncthreads();
    int buf = 0;

    for (int kt = kt_lo; kt <= kt_hi; ++kt) {
        if (kt < kt_hi) stage(buf ^ 1, kt + 1);
        int kv0 = kt * KVB;
        bool skip = (kv0 > q0 + 63);
        if (!skip) {
            const char* Kt = kt_lds[buf];
            const char* Vt = vt_lds[buf];
            // ---- QK^T (swapped: A=K, B=Q) -> S^T: lane holds q=lr, k=16nt+4lh+r ----
            floatx4 sacc[4][4];
#pragma unroll
            for (int m = 0; m < 4; m++)
#pragma unroll
                for (int nt = 0; nt < 4; nt++) sacc[m][nt] = (floatx4){0.f, 0.f, 0.f, 0.f};
#pragma unroll
            for (int ks = 0; ks < 2; ks++)
#pragma unroll
                for (int nt = 0; nt < 4; nt++) {
                    int row = nt * 16 + lr;
                    int addr = (row * 128 + ks * 64 + lh * 16) ^ ((row & 7) << 4);
                    short8 bk = *reinterpret_cast<const short8*>(Kt + addr);
#pragma unroll
                    for (int m = 0; m < 4; m++)
                        sacc[m][nt] = __builtin_amdgcn_mfma_f32_16x16x32_bf16(
                            bk, aq[m][ks], sacc[m][nt], 0, 0, 0);
                }
            // ---- causal mask: kv = kv0+16nt+4lh+r, q = q0+16m+lr ----
            if (kv0 + KVB - 1 > q0) {
#pragma unroll
                for (int m = 0; m < 4; m++)
#pragma unroll
                    for (int nt = 0; nt < 4; nt++)
#pragma unroll
                        for (int r = 0; r < 4; r++) {
                            int kcol = kv0 + nt * 16 + lh * 4 + r;
                            int qrow = q0 + m * 16 + lr;
                            if (kcol > qrow) sacc[m][nt][r] = -1e30f;
                        }
            }
            // ---- P = 2^S (lane-local rows), pack, exchange, PV ----
            int hsel = lh >> 1;
#pragma unroll
            for (int m = 0; m < 4; m++) {
                unsigned int pk[4][2];
                float ls = 0.f;
#pragma unroll
                for (int nt = 0; nt < 4; nt++) {
#pragma unroll
                    for (int r = 0; r < 4; r++) {
                        float p = __builtin_amdgcn_exp2f(sacc[m][nt][r]);
                        sacc[m][nt][r] = p;
                        ls += p;
                    }
                    pk[nt][0] = pack2bf(sacc[m][nt][0], sacc[m][nt][1]);
                    pk[nt][1] = pack2bf(sacc[m][nt][2], sacc[m][nt][3]);
                }
                lsum[m] += ls;
                // exchange: target reg (ks,t4): src lane = lr+32*(lh&1)+16*(t4>>1),
                // var pk[2ks+(lh>>1)][t4&1]
                short8 pa[2];
#pragma unroll
                for (int ks = 0; ks < 2; ks++) {
                    intx4 u;
#pragma unroll
                    for (int t4 = 0; t4 < 4; t4++) {
                        int src = lr + 32 * (lh & 1) + 16 * (t4 >> 1);
                        int r0 = __shfl((int)pk[2 * ks][t4 & 1], src);
                        int r1 = __shfl((int)pk[2 * ks + 1][t4 & 1], src);
                        u[t4] = hsel ? r1 : r0;
                    }
                    pa[ks] = __builtin_bit_cast(short8, u);
                }
#pragma unroll
                for (int ks = 0; ks < 2; ks++)
#pragma unroll
                    for (int dt = 0; dt < 4; dt++) {
                        int row = dt * 16 + lr;
                        int addr = (row * 128 + ks * 64 + lh * 16) ^ ((row & 7) << 4);
                        short8 bv = *reinterpret_cast<const short8*>(Vt + addr);
                        oacc[m][dt] = __builtin_amdgcn_mfma_f32_16x16x32_bf16(
                            pa[ks], bv, oacc[m][dt], 0, 0, 0);
                    }
            }
        }
        __syncthreads(); // drains this iter's stage + readers done with `buf`
        buf ^= 1;
    }

    // lsum[m] lives per q=lr, partial over lh: reduce across the 4 lh groups
#pragma unroll
    for (int m = 0; m < 4; m++) {
        lsum[m] += __shfl_xor(lsum[m], 16);
        lsum[m] += __shfl_xor(lsum[m], 32);
    }

    if (split) {
        int pi = bh * 21 + base + ch;
        unsigned short* Op = (pi < 448) ? OpA + (size_t)pi * 16384
                                        : OpB + (size_t)(pi - 448) * 16384;
        float* lp = lpart + (size_t)pi * 256;
#pragma unroll
        for (int m = 0; m < 4; m++) {
            if (lh == 0) lp[w * 64 + m * 16 + lr] = lsum[m];
#pragma unroll
            for (int r = 0; r < 4; r++) {
                int row = w * 64 + m * 16 + lh * 4 + r;
#pragma unroll
                for (int dt = 0; dt < 4; dt++)
                    Op[row * DH + dt * 16 + lr] = f2bf(oacc[m][dt][r]);
            }
        }
    } else {
        int b_ = bh >> 4, h_ = bh & 15;
#pragma unroll
        for (int m = 0; m < 4; m++) {
#pragma unroll
            for (int r = 0; r < 4; r++) {
                float lv = __shfl(lsum[m], lh * 4 + r); // lsum of q-row lh*4+r
                float inv = 1.f / lv;
                int srow = q0 + m * 16 + lh * 4 + r;
#pragma unroll
                for (int dt = 0; dt < 4; dt++)
                    Og[((size_t)b_ * S_LEN + srow) * E_DIM + h_ * 64 + dt * 16 + lr] =
                        f2bf(oacc[m][dt][r] * inv);
            }
        }
    }
}

// ---------------- merge KV-split partials (2..5 chunks), normalize, write Og --------
__global__ __launch_bounds__(256) void attn_reduce(const unsigned short* __restrict__ OpA,
                                                   const unsigned short* __restrict__ OpB,
                                                   const float* __restrict__ lpart,
                                                   unsigned short* __restrict__ Og) {
    int bh = blockIdx.x;      // 0..31
    int qy = blockIdx.y;      // 0..5 -> qb = 2+qy
    const int ctab[6] = {2, 3, 3, 4, 4, 5};
    const int btab[6] = {0, 2, 5, 8, 12, 16};
    int c = ctab[qy], base = btab[qy];
    int pi0 = bh * 21 + base;
    int t = threadIdx.x;
    int cg = t & 7, r0 = t >> 3;
    int b_ = bh >> 4, h_ = bh & 15;
    int qrow0 = (2 + qy) * 256;
#pragma unroll
    for (int rr = 0; rr < 8; rr++) {
        int row = r0 + rr * 32;
        float ls = 0.f;
        float s[8] = {0.f, 0.f, 0.f, 0.f, 0.f, 0.f, 0.f, 0.f};
        for (int k = 0; k < c; k++) {
            int pi = pi0 + k;
            const unsigned short* P = (pi < 448) ? OpA + (size_t)pi * 16384
                                                 : OpB + (size_t)(pi - 448) * 16384;
            ls += lpart[(size_t)pi * 256 + row];
            short8 v = *reinterpret_cast<const short8*>(P + row * DH + cg * 8);
#pragma unroll
            for (int j = 0; j < 8; j++) s[j] += bf2f((unsigned short)v[j]);
        }
        float inv = 1.f / ls;
        short8 o;
#pragma unroll
        for (int j = 0; j < 8; j++) o[j] = (short)f2bf(s[j] * inv);
        *reinterpret_cast<short8*>(Og + ((size_t)b_ * S_LEN + qrow0 + row) * E_DIM +
                                   h_ * 64 + cg * 8) = o;
    }
}

extern "C" void kernel_launch(void* const* d_in, const int* in_sizes, int n_in,
                              void* d_out, int out_size, void* d_ws, size_t ws_size,
                              hipStream_t stream) {
    const float* x  = (const float*)d_in[0];
    const float* Wq = (const float*)d_in[1];
    const float* bq = (const float*)d_in[2];
    const float* Wk = (const float*)d_in[3];
    const float* bk = (const float*)d_in[4];
    const float* Wv = (const float*)d_in[5];
    const float* bv = (const float*)d_in[6];
    const float* Wo = (const float*)d_in[7];
    const float* bo = (const float*)d_in[8];
    float* out = (float*)d_out;

    const size_t NX = (size_t)M_ROWS * E_DIM; // 4M elems
    const size_t NW = (size_t)E_DIM * E_DIM;  // 1M elems
    unsigned short* ws  = (unsigned short*)d_ws;
    unsigned short* Xb  = ws;
    unsigned short* Wqt = Xb + NX;   // Wqt|Wkt|Wvt contiguous = Wcat [3072][1024]
    unsigned short* Wkt = Wqt + NW;
    unsigned short* Wvt = Wkt + NW;
    unsigned short* Wot = Wvt + NW;
    unsigned short* Qg  = Wot + NW;
    unsigned short* Kg  = Qg + NX;
    unsigned short* Vtg = Kg + NX;
    unsigned short* Og  = Vtg + NX;
    // Partial slots (32KB = 16384 u16 each), 672 total:
    //   slots 0..447   overlay Xb|Wqt|Wkt|Wvt (7M u16, dead after gemm_qkv8)
    //   slots 448..671 + lpart in the region after Og (proven writable, rounds 3-7)
    unsigned short* OpA = Xb;
    unsigned short* OpB = Og + NX;
    float* lpart = (float*)(OpB + (size_t)224 * 16384);

    prep<<<dim3(8192), 256, 0, stream>>>(x, Xb, Wq, Wk, Wv, Wo, Wqt, Wkt, Wvt, Wot);

    gemm_qkv8<<<dim3(192), 512, 0, stream>>>(Wqt, Xb, bq, bk, bv, Qg, Kg, Vtg);

    attn_fwd<<<dim3(736), 256, 0, stream>>>(Qg, Kg, Vtg, Og, OpA, OpB, lpart);
    attn_reduce<<<dim3(B_SZ * NH, 6), 256, 0, stream>>>(OpA, OpB, lpart, Og);

    gemm_o<<<dim3(E_DIM / 64, M_ROWS / 128), 256, 0, stream>>>(Og, Wot, bo, out);
}

// Round 12
// 113.937 us; speedup vs baseline: 1.1034x; 1.1034x over previous
//
#include <hip/hip_runtime.h>
#include <hip/hip_bf16.h>

#define B_SZ 2
#define S_LEN 2048
#define E_DIM 1024
#define NH 16
#define DH 64
#define M_ROWS (B_SZ * S_LEN) /* 4096 */
#define QB 128
#define KVB 64

typedef __attribute__((ext_vector_type(8))) short short8;
typedef __attribute__((ext_vector_type(4))) float floatx4;
typedef __attribute__((ext_vector_type(4))) int intx4;

static __device__ __forceinline__ unsigned short f2bf(float f) {
    __hip_bfloat16 h = __float2bfloat16(f);
    return *reinterpret_cast<unsigned short*>(&h);
}
static __device__ __forceinline__ float bf2f(unsigned short u) {
    unsigned int v = ((unsigned int)u) << 16;
    return __builtin_bit_cast(float, v);
}
static __device__ __forceinline__ unsigned int pack2bf(float lo, float hi) {
    return (unsigned int)f2bf(lo) | ((unsigned int)f2bf(hi) << 16);
}

static __device__ __forceinline__ void gl2lds16(const void* g, void* l) {
    __builtin_amdgcn_global_load_lds((const __attribute__((address_space(1))) void*)g,
                                     (__attribute__((address_space(3))) void*)l, 16, 0, 0);
}

#define WAIT_VM0() asm volatile("s_waitcnt vmcnt(0)" ::: "memory")
#define WAIT_LGKM0() asm volatile("s_waitcnt lgkmcnt(0)" ::: "memory")

// ---------------- prep: fp32->bf16 convert (x) + 4 weight transposes, fused --------
__global__ __launch_bounds__(256) void prep(const float* __restrict__ x,
                                            unsigned short* __restrict__ Xb,
                                            const float* __restrict__ W0,
                                            const float* __restrict__ W1,
                                            const float* __restrict__ W2,
                                            const float* __restrict__ W3,
                                            unsigned short* __restrict__ T0,
                                            unsigned short* __restrict__ T1,
                                            unsigned short* __restrict__ T2,
                                            unsigned short* __restrict__ T3) {
    __shared__ float tile[32][33];
    int bid = blockIdx.x;
    int t = threadIdx.x;
    if (bid < 4096) { // cvt: 4096 blocks x 1024 elems
        int i = (bid * 256 + t) * 4;
        float4 v = *reinterpret_cast<const float4*>(x + i);
        ushort4 o;
        o.x = f2bf(v.x); o.y = f2bf(v.y); o.z = f2bf(v.z); o.w = f2bf(v.w);
        *reinterpret_cast<ushort4*>(Xb + i) = o;
        return;
    }
    int u = bid - 4096;
    int z = u >> 10, rest = u & 1023;
    int bx = (rest & 31) * 32, by = (rest >> 5) * 32;
    const float* W = (z == 0) ? W0 : (z == 1) ? W1 : (z == 2) ? W2 : W3;
    unsigned short* Wt = (z == 0) ? T0 : (z == 1) ? T1 : (z == 2) ? T2 : T3;
    int tx = t & 31, ty = t >> 5; // 32 x 8
#pragma unroll
    for (int i = 0; i < 32; i += 8)
        tile[ty + i][tx] = W[(size_t)(by + ty + i) * E_DIM + bx + tx];
    __syncthreads();
#pragma unroll
    for (int i = 0; i < 32; i += 8)
        Wt[(size_t)(bx + ty + i) * E_DIM + by + tx] = f2bf(tile[tx][ty + i]);
}

// Q scale folds 1/sqrt(D) AND log2(e) so attention can use raw v_exp_f32 (2^x).
#define QSCALE 0.18033688011112042f

// ---------------- fused QKV projection: 8-phase 256x256 schedule --------------------
__global__ __launch_bounds__(512, 2) void gemm_qkv8(const unsigned short* __restrict__ Wcat,
                                                    const unsigned short* __restrict__ Xb,
                                                    const float* __restrict__ bq,
                                                    const float* __restrict__ bk,
                                                    const float* __restrict__ bv,
                                                    unsigned short* __restrict__ Qg,
                                                    unsigned short* __restrict__ Kg,
                                                    unsigned short* __restrict__ Vtg) {
    __shared__ __align__(16) char lds[2][2][32768]; // [buf][A=0/B=1][256 rows x 128B]

    int t = threadIdx.x;
    int b = blockIdx.x;
    int xcd = b & 7, ii = b >> 3;
    int it = (xcd & 3) * 3 + (ii >> 3); // 0..11
    int jt = (xcd >> 2) * 8 + (ii & 7); // 0..15
    int iBase = it << 8, jBase = jt << 8;

    int w = t >> 6, lane = t & 63;
    int lr = lane & 15, lh = lane >> 4;
    int wm = w >> 2, wn = w & 3; // 2m x 4n waves

    int srow = t >> 3;             // 0..63
    int scbx = ((t & 7) << 4) ^ ((srow & 7) << 4);

    const char* Ab = (const char*)Wcat;
    const char* Bb = (const char*)Xb;

    floatx4 acc[8][4];
#pragma unroll
    for (int i = 0; i < 8; i++)
#pragma unroll
        for (int j = 0; j < 4; j++) acc[i][j] = (floatx4){0.f, 0.f, 0.f, 0.f};

    auto stageA = [&](int buf, int kt) {
        int k0b = kt << 7;
#pragma unroll
        for (int c = 0; c < 4; c++)
            gl2lds16(Ab + (size_t)(iBase + c * 64 + srow) * 2048 + k0b + scbx,
                     &lds[buf][0][c * 8192 + t * 16]);
    };
    auto stageB = [&](int buf, int kt) {
        int k0b = kt << 7;
#pragma unroll
        for (int c = 0; c < 4; c++)
            gl2lds16(Bb + (size_t)(jBase + c * 64 + srow) * 2048 + k0b + scbx,
                     &lds[buf][1][c * 8192 + t * 16]);
    };

    short8 af[4][2], bf[4][2];
    auto rdA = [&](int buf, int qm) {
#pragma unroll
        for (int mi = 0; mi < 4; mi++)
#pragma unroll
            for (int ks = 0; ks < 2; ks++) {
                int row = wm * 128 + qm * 64 + mi * 16 + lr;
                af[mi][ks] = *reinterpret_cast<const short8*>(
                    &lds[buf][0][(row * 128 + ks * 64 + lh * 16) ^ ((row & 7) << 4)]);
            }
    };
    auto rdB = [&](int buf, int qn) {
#pragma unroll
        for (int ni = 0; ni < 2; ni++)
#pragma unroll
            for (int ks = 0; ks < 2; ks++) {
                int row = wn * 64 + qn * 32 + ni * 16 + lr;
                bf[qn * 2 + ni][ks] = *reinterpret_cast<const short8*>(
                    &lds[buf][1][(row * 128 + ks * 64 + lh * 16) ^ ((row & 7) << 4)]);
            }
    };
    auto mfma16 = [&](int qm, int qn) {
        __builtin_amdgcn_s_setprio(1);
#pragma unroll
        for (int mi = 0; mi < 4; mi++)
#pragma unroll
            for (int ni = 0; ni < 2; ni++)
#pragma unroll
                for (int ks = 0; ks < 2; ks++)
                    acc[qm * 4 + mi][qn * 2 + ni] = __builtin_amdgcn_mfma_f32_16x16x32_bf16(
                        af[mi][ks], bf[qn * 2 + ni][ks], acc[qm * 4 + mi][qn * 2 + ni], 0, 0, 0);
        __builtin_amdgcn_s_setprio(0);
    };

    const int NT = 16; // K=1024 / 64
    stageA(0, 0);
    stageB(0, 0);
    WAIT_VM0();
    __builtin_amdgcn_s_barrier();

    for (int kt = 0; kt < NT; ++kt) {
        int cur = kt & 1, nxt = cur ^ 1;
        bool pf = (kt + 1 < NT);
        // ---- phase 0: quadrant (0,0); prefetch next A ----
        rdA(cur, 0);
        rdB(cur, 0);
        if (pf) stageA(nxt, kt + 1);
        __builtin_amdgcn_s_barrier();
        WAIT_LGKM0();
        __builtin_amdgcn_sched_barrier(0);
        mfma16(0, 0);
        __builtin_amdgcn_s_barrier();
        // ---- phase 1: quadrant (0,1); prefetch next B ----
        rdB(cur, 1);
        if (pf) stageB(nxt, kt + 1);
        __builtin_amdgcn_s_barrier();
        WAIT_LGKM0();
        __builtin_amdgcn_sched_barrier(0);
        mfma16(0, 1);
        __builtin_amdgcn_s_barrier();
        // ---- phase 2: quadrant (1,0) ----
        rdA(cur, 1);
        __builtin_amdgcn_s_barrier();
        WAIT_LGKM0();
        __builtin_amdgcn_sched_barrier(0);
        mfma16(1, 0);
        __builtin_amdgcn_s_barrier();
        // ---- phase 3: quadrant (1,1); drain prefetch before next-iter reads ----
        if (pf) WAIT_VM0();
        __builtin_amdgcn_s_barrier();
        mfma16(1, 1);
        __builtin_amdgcn_s_barrier();
    }

    // ---------------- epilogue ----------------
    int wsel = iBase >> 10;
    const float* bias = (wsel == 0) ? bq : (wsel == 1) ? bk : bv;
    __syncthreads(); // LDS free for reuse

    if (wsel < 2) {
        unsigned short* O = wsel ? Kg : Qg;
        float scale = wsel ? 1.0f : QSCALE;
#pragma unroll
        for (int mi8 = 0; mi8 < 8; mi8++) {
            int i = iBase + wm * 128 + mi8 * 16 + lh * 4;
            int im = i & 1023;
            int h = im >> 6, d0 = im & 63;
            float4 bs = *reinterpret_cast<const float4*>(&bias[im]);
#pragma unroll
            for (int nf = 0; nf < 4; nf++) {
                int j = jBase + wn * 64 + nf * 16 + lr;
                int b_ = j >> 11, s = j & (S_LEN - 1);
                ushort4 pk;
                pk.x = f2bf((acc[mi8][nf][0] + bs.x) * scale);
                pk.y = f2bf((acc[mi8][nf][1] + bs.y) * scale);
                pk.z = f2bf((acc[mi8][nf][2] + bs.z) * scale);
                pk.w = f2bf((acc[mi8][nf][3] + bs.w) * scale);
                *reinterpret_cast<ushort4*>(
                    &O[((size_t)(b_ * NH + h) * S_LEN + s) * DH + d0]) = pk;
            }
        }
    } else {
        // V: transpose each wave's 128x64 slab through LDS -> [b][h][d][s] coalesced
        char* lw = &lds[0][0][0] + w * 16384;
#pragma unroll
        for (int mi8 = 0; mi8 < 8; mi8++) {
            int i = iBase + wm * 128 + mi8 * 16 + lh * 4;
            float4 bs = *reinterpret_cast<const float4*>(&bias[i & 1023]);
#pragma unroll
            for (int nf = 0; nf < 4; nf++) {
                int jl = nf * 16 + lr;
#pragma unroll
                for (int r = 0; r < 4; r++) {
                    int il = mi8 * 16 + lh * 4 + r;
                    float bb = (r == 0) ? bs.x : (r == 1) ? bs.y : (r == 2) ? bs.z : bs.w;
                    *reinterpret_cast<unsigned short*>(
                        lw + ((il * 128 + jl * 2) ^ ((il & 7) << 4))) =
                        f2bf(acc[mi8][nf][r] + bb);
                }
            }
        }
        __syncthreads();
#pragma unroll
        for (int rep = 0; rep < 16; rep++) {
            int idx = rep * 64 + lane;
            int il = idx >> 3, jb = idx & 7;
            short8 vv = *reinterpret_cast<const short8*>(
                lw + ((il * 128 + jb * 16) ^ ((il & 7) << 4)));
            int i = iBase + wm * 128 + il;
            int im = i & 1023;
            int h = im >> 6, d = im & 63;
            int j = jBase + wn * 64 + jb * 8;
            int b_ = j >> 11, s = j & (S_LEN - 1);
            *reinterpret_cast<short8*>(
                &Vtg[((size_t)(b_ * NH + h) * DH + d) * S_LEN + s]) = vv;
        }
    }
}

// ---------------- output projection: 8-phase counted-vmcnt, 128x128, C^T ------------
// out[j=token][i=feature] = sum_k Og[j][k] * Wot_t[i][k] + bo[i].
// Grid 256 (8 i-tiles x 32 j-tiles) = 1 block/CU, 512 thr / 8 waves (2m x 4n,
// wave 64x32). 2 phases per K-step, vmcnt(0) once per K-step (loads span barriers).
__global__ __launch_bounds__(512, 2) void gemm_o8(const unsigned short* __restrict__ Wot,
                                                  const unsigned short* __restrict__ Og,
                                                  const float* __restrict__ bo,
                                                  float* __restrict__ out) {
    __shared__ __align__(16) char lds[2][2][16384]; // [buf][A=0/B=1][128 rows x 128B]

    int t = threadIdx.x;
    int b = blockIdx.x;
    int xcd = b & 7, ii = b >> 3;       // ii in [0,32)
    int it = ii & 7;                    // all 8 i-tiles per XCD (Wot 2MB)
    int jt = (xcd << 2) | (ii >> 3);    // 4 j-tiles per XCD (Og 1MB)
    int iBase = it << 7, jBase = jt << 7;

    int w = t >> 6, lane = t & 63;
    int lr = lane & 15, lh = lane >> 4;
    int wm = w >> 2, wn = w & 3; // 2m x 4n

    int srow = t >> 3; // 0..63
    int scbx = ((t & 7) << 4) ^ ((srow & 7) << 4);

    const char* Ab = (const char*)Wot;
    const char* Bb = (const char*)Og;

    floatx4 acc[4][2];
#pragma unroll
    for (int i = 0; i < 4; i++)
#pragma unroll
        for (int j = 0; j < 2; j++) acc[i][j] = (floatx4){0.f, 0.f, 0.f, 0.f};

    auto stageA = [&](int buf, int kt) {
        int k0b = kt << 7;
#pragma unroll
        for (int c = 0; c < 2; c++)
            gl2lds16(Ab + (size_t)(iBase + c * 64 + srow) * 2048 + k0b + scbx,
                     &lds[buf][0][c * 8192 + t * 16]);
    };
    auto stageB = [&](int buf, int kt) {
        int k0b = kt << 7;
#pragma unroll
        for (int c = 0; c < 2; c++)
            gl2lds16(Bb + (size_t)(jBase + c * 64 + srow) * 2048 + k0b + scbx,
                     &lds[buf][1][c * 8192 + t * 16]);
    };

    short8 af[4][2], bf[2][2];
    auto rdA = [&](int buf, int qm) {
#pragma unroll
        for (int m2 = 0; m2 < 2; m2++)
#pragma unroll
            for (int ks = 0; ks < 2; ks++) {
                int mi = qm * 2 + m2;
                int row = wm * 64 + mi * 16 + lr;
                af[mi][ks] = *reinterpret_cast<const short8*>(
                    &lds[buf][0][(row * 128 + ks * 64 + lh * 16) ^ ((row & 7) << 4)]);
            }
    };
    auto rdB = [&](int buf) {
#pragma unroll
        for (int nf = 0; nf < 2; nf++)
#pragma unroll
            for (int ks = 0; ks < 2; ks++) {
                int row = wn * 32 + nf * 16 + lr;
                bf[nf][ks] = *reinterpret_cast<const short8*>(
                    &lds[buf][1][(row * 128 + ks * 64 + lh * 16) ^ ((row & 7) << 4)]);
            }
    };
    auto mfma8 = [&](int qm) {
        __builtin_amdgcn_s_setprio(1);
#pragma unroll
        for (int m2 = 0; m2 < 2; m2++)
#pragma unroll
            for (int nf = 0; nf < 2; nf++)
#pragma unroll
                for (int ks = 0; ks < 2; ks++) {
                    int mi = qm * 2 + m2;
                    acc[mi][nf] = __builtin_amdgcn_mfma_f32_16x16x32_bf16(
                        af[mi][ks], bf[nf][ks], acc[mi][nf], 0, 0, 0);
                }
        __builtin_amdgcn_s_setprio(0);
    };

    const int NT = 16; // K=1024 / 64
    stageA(0, 0);
    stageB(0, 0);
    WAIT_VM0();
    __builtin_amdgcn_s_barrier();

    for (int kt = 0; kt < NT; ++kt) {
        int cur = kt & 1, nxt = cur ^ 1;
        bool pf = (kt + 1 < NT);
        // ---- phase 0: A-quadrant 0 + both B; prefetch next A ----
        rdA(cur, 0);
        rdB(cur);
        if (pf) stageA(nxt, kt + 1);
        __builtin_amdgcn_s_barrier();
        WAIT_LGKM0();
        __builtin_amdgcn_sched_barrier(0);
        mfma8(0);
        __builtin_amdgcn_s_barrier();
        // ---- phase 1: A-quadrant 1; prefetch next B; drain once per K-step ----
        rdA(cur, 1);
        if (pf) stageB(nxt, kt + 1);
        __builtin_amdgcn_s_barrier();
        WAIT_LGKM0();
        __builtin_amdgcn_sched_barrier(0);
        mfma8(1);
        if (pf) WAIT_VM0();
        __builtin_amdgcn_s_barrier();
    }

    // ---- epilogue: lane holds 4 consecutive features -> float4 stores ----
#pragma unroll
    for (int mi = 0; mi < 4; mi++) {
        int i = iBase + wm * 64 + mi * 16 + lh * 4;
        float4 bs = *reinterpret_cast<const float4*>(&bo[i]);
#pragma unroll
        for (int nf = 0; nf < 2; nf++) {
            int j = jBase + wn * 32 + nf * 16 + lr;
            float4 o;
            o.x = acc[mi][nf][0] + bs.x;
            o.y = acc[mi][nf][1] + bs.y;
            o.z = acc[mi][nf][2] + bs.z;
            o.w = acc[mi][nf][3] + bs.w;
            *reinterpret_cast<float4*>(&out[(size_t)j * E_DIM + i]) = o;
        }
    }
}

// ---------------- causal flash attention: swapped QK^T, in-register P ---------------
// (round-10 version: 32KB LDS, 4 blocks/CU, 960-block balanced KV-split)
__global__ __launch_bounds__(256, 4) void attn_fwd(const unsigned short* __restrict__ Qg,
                                                   const unsigned short* __restrict__ Kg,
                                                   const unsigned short* __restrict__ Vtg,
                                                   unsigned short* __restrict__ Og,
                                                   unsigned short* __restrict__ Opart,
                                                   float* __restrict__ lpart) {
    __shared__ __align__(16) char kt_lds[2][KVB * 128];
    __shared__ __align__(16) char vt_lds[2][KVB * 128];

    int bid = blockIdx.x;
    int xcd = bid & 7, ii = bid >> 3;  // [0,120)
    int bh = (xcd << 2) + ii / 30;
    int jj = 29 - (ii % 30);           // dispatch big-qb chunks first
    int qb, ch, c;
    if (jj < 6)        { qb = jj; ch = 0; c = 1; }
    else if (jj < 18)  { int u = jj - 6;  qb = 6 + (u >> 1); ch = u & 1; c = 2; }
    else               { int u = jj - 18; qb = 12 + u / 3;   ch = u % 3; c = 3; }
    int T = 2 * qb + 2;
    int kt_lo = ch * T / c;
    int kt_hi = (ch + 1) * T / c - 1;
    bool split = (c > 1);

    int w = threadIdx.x >> 6, lane = threadIdx.x & 63;
    int lr = lane & 15, lh = lane >> 4;
    int q0 = qb * QB + w * 32;

    const char* Kb = (const char*)(Kg + (size_t)bh * S_LEN * DH);
    const char* Vb = (const char*)(Vtg + (size_t)bh * DH * S_LEN);
    const unsigned short* Qb = Qg + (size_t)bh * S_LEN * DH;

    int wi0 = w * 2;
    int srow0 = wi0 * 8 + (lane >> 3);
    int scol = (lane & 7) << 4;

    auto stage = [&](int buf, int kt) { // K + V tiles, 2+2 x 1KB per wave
        int kv0 = kt * KVB;
#pragma unroll
        for (int i = 0; i < 2; ++i) {
            int row = srow0 + i * 8;
            int colb = scol ^ ((row & 7) << 4);
            gl2lds16(Kb + (size_t)(kv0 + row) * 128 + colb,
                     kt_lds[buf] + (wi0 + i) * 1024);
            gl2lds16(Vb + (size_t)row * (S_LEN * 2) + (size_t)kv0 * 2 + colb,
                     vt_lds[buf] + (wi0 + i) * 1024);
        }
    };

    short8 aq[2][2];
#pragma unroll
    for (int m = 0; m < 2; m++)
#pragma unroll
        for (int ks = 0; ks < 2; ks++)
            aq[m][ks] = *reinterpret_cast<const short8*>(
                Qb + (size_t)(q0 + m * 16 + lr) * DH + ks * 32 + lh * 8);

    floatx4 oacc[2][4];
    float lsum[2];
#pragma unroll
    for (int m = 0; m < 2; m++) {
#pragma unroll
        for (int dt = 0; dt < 4; dt++) oacc[m][dt] = (floatx4){0.f, 0.f, 0.f, 0.f};
        lsum[m] = 0.f;
    }

    stage(0, kt_lo);
    __syncthreads();
    int buf = 0;

    for (int kt = kt_lo; kt <= kt_hi; ++kt) {
        if (kt < kt_hi) stage(buf ^ 1, kt + 1);
        int kv0 = kt * KVB;
        bool skip = (kv0 > q0 + 31);
        if (!skip) {
            const char* Kt = kt_lds[buf];
            const char* Vt = vt_lds[buf];
            // ---- QK^T (swapped: A=K, B=Q) -> S^T: lane holds q=lr, k=16nt+4lh+r ----
            floatx4 sacc[2][4];
#pragma unroll
            for (int m = 0; m < 2; m++)
#pragma unroll
                for (int nt = 0; nt < 4; nt++) sacc[m][nt] = (floatx4){0.f, 0.f, 0.f, 0.f};
#pragma unroll
            for (int ks = 0; ks < 2; ks++)
#pragma unroll
                for (int nt = 0; nt < 4; nt++) {
                    int row = nt * 16 + lr;
                    int addr = (row * 128 + ks * 64 + lh * 16) ^ ((row & 7) << 4);
                    short8 bk = *reinterpret_cast<const short8*>(Kt + addr);
#pragma unroll
                    for (int m = 0; m < 2; m++)
                        sacc[m][nt] = __builtin_amdgcn_mfma_f32_16x16x32_bf16(
                            bk, aq[m][ks], sacc[m][nt], 0, 0, 0);
                }
            // ---- causal mask (diagonal band only): kv = kv0+16nt+4lh+r, q = q0+16m+lr
            if (kv0 + KVB - 1 > q0) {
#pragma unroll
                for (int m = 0; m < 2; m++)
#pragma unroll
                    for (int nt = 0; nt < 4; nt++)
#pragma unroll
                        for (int r = 0; r < 4; r++) {
                            int kcol = kv0 + nt * 16 + lh * 4 + r;
                            int qrow = q0 + m * 16 + lr;
                            if (kcol > qrow) sacc[m][nt][r] = -1e30f;
                        }
            }
            // ---- P = 2^S (lane-local rows), pack to bf16 pairs ----
            unsigned int pk[2][4][2];
#pragma unroll
            for (int m = 0; m < 2; m++) {
                float ls = 0.f;
#pragma unroll
                for (int nt = 0; nt < 4; nt++) {
#pragma unroll
                    for (int r = 0; r < 4; r++) {
                        float p = __builtin_amdgcn_exp2f(sacc[m][nt][r]);
                        sacc[m][nt][r] = p;
                        ls += p;
                    }
                    pk[m][nt][0] = pack2bf(sacc[m][nt][0], sacc[m][nt][1]);
                    pk[m][nt][1] = pack2bf(sacc[m][nt][2], sacc[m][nt][3]);
                }
                lsum[m] += ls;
            }
            // ---- exchange: build A-frag P[q=lr][k=32ks+8lh+e] from pk ----
            short8 pa[2][2];
            int hsel = lh >> 1;
#pragma unroll
            for (int m = 0; m < 2; m++)
#pragma unroll
                for (int ks = 0; ks < 2; ks++) {
                    intx4 u;
#pragma unroll
                    for (int t4 = 0; t4 < 4; t4++) {
                        int src = lr + 32 * (lh & 1) + 16 * (t4 >> 1);
                        int r0 = __shfl((int)pk[m][2 * ks][t4 & 1], src);
                        int r1 = __shfl((int)pk[m][2 * ks + 1][t4 & 1], src);
                        u[t4] = hsel ? r1 : r0;
                    }
                    pa[m][ks] = __builtin_bit_cast(short8, u);
                }
            // ---- PV (O row=q=4lh+r, col=d=lr) ----
#pragma unroll
            for (int ks = 0; ks < 2; ks++)
#pragma unroll
                for (int dt = 0; dt < 4; dt++) {
                    int row = dt * 16 + lr;
                    int addr = (row * 128 + ks * 64 + lh * 16) ^ ((row & 7) << 4);
                    short8 bv = *reinterpret_cast<const short8*>(Vt + addr);
#pragma unroll
                    for (int m = 0; m < 2; m++)
                        oacc[m][dt] = __builtin_amdgcn_mfma_f32_16x16x32_bf16(
                            pa[m][ks], bv, oacc[m][dt], 0, 0, 0);
                }
        }
        __syncthreads(); // drains this iter's stage + readers done with `buf`
        buf ^= 1;
    }

    // lsum[m] lives per q=lr, partial over lh: reduce across the 4 lh groups
#pragma unroll
    for (int m = 0; m < 2; m++) {
        lsum[m] += __shfl_xor(lsum[m], 16);
        lsum[m] += __shfl_xor(lsum[m], 32);
    }

    if (split) {
        int base = (qb < 12) ? (qb - 6) * 2 : 12 + (qb - 12) * 3;
        int pi = bh * 24 + base + ch;
        unsigned short* Op = Opart + (size_t)pi * (QB * DH);
        float* lp = lpart + (size_t)pi * QB;
#pragma unroll
        for (int m = 0; m < 2; m++) {
            if (lh == 0) lp[w * 32 + m * 16 + lr] = lsum[m];
#pragma unroll
            for (int r = 0; r < 4; r++) {
                int row = w * 32 + m * 16 + lh * 4 + r;
#pragma unroll
                for (int dt = 0; dt < 4; dt++)
                    Op[row * DH + dt * 16 + lr] = f2bf(oacc[m][dt][r]);
            }
        }
    } else {
        int b_ = bh >> 4, h_ = bh & 15;
#pragma unroll
        for (int m = 0; m < 2; m++) {
#pragma unroll
            for (int r = 0; r < 4; r++) {
                float lv = __shfl(lsum[m], lh * 4 + r); // lsum of q-row lh*4+r
                float inv = 1.f / lv;
                int srow = q0 + m * 16 + lh * 4 + r;
#pragma unroll
                for (int dt = 0; dt < 4; dt++)
                    Og[((size_t)b_ * S_LEN + srow) * E_DIM + h_ * 64 + dt * 16 + lr] =
                        f2bf(oacc[m][dt][r] * inv);
            }
        }
    }
}

// ---------------- merge KV-split partials (2 or 3 chunks), normalize, write Og ------
__global__ __launch_bounds__(256) void attn_reduce(const unsigned short* __restrict__ Opart,
                                                   const float* __restrict__ lpart,
                                                   unsigned short* __restrict__ Og) {
    int bh = blockIdx.x;      // 0..31
    int qb = 6 + blockIdx.y;  // 6..15
    int c = (qb < 12) ? 2 : 3;
    int base = (qb < 12) ? (qb - 6) * 2 : 12 + (qb - 12) * 3;
    int pi0 = bh * 24 + base;
    const unsigned short* P0 = Opart + (size_t)pi0 * (QB * DH);
    const float* l0 = lpart + (size_t)pi0 * QB;
    int t = threadIdx.x;
    int cg = t & 7, r0 = t >> 3;
    int b_ = bh >> 4, h_ = bh & 15;
    int qrow0 = qb * QB;
#pragma unroll
    for (int rr = 0; rr < 4; rr++) {
        int row = r0 + rr * 32;
        float ls = l0[row] + l0[QB + row];
        if (c == 3) ls += l0[2 * QB + row];
        float inv = 1.f / ls;
        short8 v0 = *reinterpret_cast<const short8*>(P0 + row * DH + cg * 8);
        short8 v1 = *reinterpret_cast<const short8*>(P0 + QB * DH + row * DH + cg * 8);
        float s[8];
#pragma unroll
        for (int j = 0; j < 8; j++)
            s[j] = bf2f((unsigned short)v0[j]) + bf2f((unsigned short)v1[j]);
        if (c == 3) {
            short8 v2 = *reinterpret_cast<const short8*>(P0 + 2 * QB * DH + row * DH + cg * 8);
#pragma unroll
            for (int j = 0; j < 8; j++) s[j] += bf2f((unsigned short)v2[j]);
        }
        short8 o;
#pragma unroll
        for (int j = 0; j < 8; j++) o[j] = (short)f2bf(s[j] * inv);
        *reinterpret_cast<short8*>(Og + ((size_t)b_ * S_LEN + qrow0 + row) * E_DIM +
                                   h_ * 64 + cg * 8) = o;
    }
}

extern "C" void kernel_launch(void* const* d_in, const int* in_sizes, int n_in,
                              void* d_out, int out_size, void* d_ws, size_t ws_size,
                              hipStream_t stream) {
    const float* x  = (const float*)d_in[0];
    const float* Wq = (const float*)d_in[1];
    const float* bq = (const float*)d_in[2];
    const float* Wk = (const float*)d_in[3];
    const float* bk = (const float*)d_in[4];
    const float* Wv = (const float*)d_in[5];
    const float* bv = (const float*)d_in[6];
    const float* Wo = (const float*)d_in[7];
    const float* bo = (const float*)d_in[8];
    float* out = (float*)d_out;

    const size_t NX = (size_t)M_ROWS * E_DIM; // 4M elems
    const size_t NW = (size_t)E_DIM * E_DIM;  // 1M elems
    unsigned short* ws  = (unsigned short*)d_ws;
    unsigned short* Xb  = ws;
    unsigned short* Wqt = Xb + NX;   // Wqt|Wkt|Wvt contiguous = Wcat [3072][1024]
    unsigned short* Wkt = Wqt + NW;
    unsigned short* Wvt = Wkt + NW;
    unsigned short* Wot = Wvt + NW;
    unsigned short* Qg  = Wot + NW;
    unsigned short* Kg  = Qg + NX;
    unsigned short* Vtg = Kg + NX;
    unsigned short* Og  = Vtg + NX;
    // Partials OVERLAY the Xb/Wqt/Wkt/Wvt region (dead after gemm_qkv8):
    // 32 bh * 24 slots * 8192 u16 = 12.6 MB + lpart 393KB  <  14 MB (Xb..Wvt)
    unsigned short* Opart = Xb;
    float* lpart = (float*)(Opart + (size_t)32 * 24 * QB * DH);

    prep<<<dim3(8192), 256, 0, stream>>>(x, Xb, Wq, Wk, Wv, Wo, Wqt, Wkt, Wvt, Wot);

    gemm_qkv8<<<dim3(192), 512, 0, stream>>>(Wqt, Xb, bq, bk, bv, Qg, Kg, Vtg);

    attn_fwd<<<dim3(960), 256, 0, stream>>>(Qg, Kg, Vtg, Og, Opart, lpart);
    attn_reduce<<<dim3(B_SZ * NH, 10), 256, 0, stream>>>(Opart, lpart, Og);

    gemm_o8<<<dim3(256), 512, 0, stream>>>(Wot, Og, bo, out);
}

// Round 13
// 113.862 us; speedup vs baseline: 1.1041x; 1.0007x over previous
//
#include <hip/hip_runtime.h>
#include <hip/hip_bf16.h>

#define B_SZ 2
#define S_LEN 2048
#define E_DIM 1024
#define NH 16
#define DH 64
#define M_ROWS (B_SZ * S_LEN) /* 4096 */
#define QB 128
#define KVB 64

typedef __attribute__((ext_vector_type(8))) short short8;
typedef __attribute__((ext_vector_type(4))) float floatx4;
typedef __attribute__((ext_vector_type(4))) int intx4;

static __device__ __forceinline__ unsigned short f2bf(float f) {
    __hip_bfloat16 h = __float2bfloat16(f);
    return *reinterpret_cast<unsigned short*>(&h);
}
static __device__ __forceinline__ float bf2f(unsigned short u) {
    unsigned int v = ((unsigned int)u) << 16;
    return __builtin_bit_cast(float, v);
}
static __device__ __forceinline__ unsigned int pack2bf(float lo, float hi) {
    return (unsigned int)f2bf(lo) | ((unsigned int)f2bf(hi) << 16);
}

static __device__ __forceinline__ void gl2lds16(const void* g, void* l) {
    __builtin_amdgcn_global_load_lds((const __attribute__((address_space(1))) void*)g,
                                     (__attribute__((address_space(3))) void*)l, 16, 0, 0);
}

#define WAIT_VM0() asm volatile("s_waitcnt vmcnt(0)" ::: "memory")
#define WAIT_LGKM0() asm volatile("s_waitcnt lgkmcnt(0)" ::: "memory")

// ---------------- prep: fp32->bf16 convert (x) + 4 weight transposes, fused --------
__global__ __launch_bounds__(256) void prep(const float* __restrict__ x,
                                            unsigned short* __restrict__ Xb,
                                            const float* __restrict__ W0,
                                            const float* __restrict__ W1,
                                            const float* __restrict__ W2,
                                            const float* __restrict__ W3,
                                            unsigned short* __restrict__ T0,
                                            unsigned short* __restrict__ T1,
                                            unsigned short* __restrict__ T2,
                                            unsigned short* __restrict__ T3) {
    __shared__ float tile[32][33];
    int bid = blockIdx.x;
    int t = threadIdx.x;
    if (bid < 4096) { // cvt: 4096 blocks x 1024 elems
        int i = (bid * 256 + t) * 4;
        float4 v = *reinterpret_cast<const float4*>(x + i);
        ushort4 o;
        o.x = f2bf(v.x); o.y = f2bf(v.y); o.z = f2bf(v.z); o.w = f2bf(v.w);
        *reinterpret_cast<ushort4*>(Xb + i) = o;
        return;
    }
    int u = bid - 4096;
    int z = u >> 10, rest = u & 1023;
    int bx = (rest & 31) * 32, by = (rest >> 5) * 32;
    const float* W = (z == 0) ? W0 : (z == 1) ? W1 : (z == 2) ? W2 : W3;
    unsigned short* Wt = (z == 0) ? T0 : (z == 1) ? T1 : (z == 2) ? T2 : T3;
    int tx = t & 31, ty = t >> 5; // 32 x 8
#pragma unroll
    for (int i = 0; i < 32; i += 8)
        tile[ty + i][tx] = W[(size_t)(by + ty + i) * E_DIM + bx + tx];
    __syncthreads();
#pragma unroll
    for (int i = 0; i < 32; i += 8)
        Wt[(size_t)(bx + ty + i) * E_DIM + by + tx] = f2bf(tile[tx][ty + i]);
}

// Q scale folds 1/sqrt(D) AND log2(e) so attention can use raw v_exp_f32 (2^x).
#define QSCALE 0.18033688011112042f

// ---------------- fused QKV projection: 8-phase 256x256 schedule --------------------
__global__ __launch_bounds__(512, 2) void gemm_qkv8(const unsigned short* __restrict__ Wcat,
                                                    const unsigned short* __restrict__ Xb,
                                                    const float* __restrict__ bq,
                                                    const float* __restrict__ bk,
                                                    const float* __restrict__ bv,
                                                    unsigned short* __restrict__ Qg,
                                                    unsigned short* __restrict__ Kg,
                                                    unsigned short* __restrict__ Vtg) {
    __shared__ __align__(16) char lds[2][2][32768]; // [buf][A=0/B=1][256 rows x 128B]

    int t = threadIdx.x;
    int b = blockIdx.x;
    int xcd = b & 7, ii = b >> 3;
    int it = (xcd & 3) * 3 + (ii >> 3); // 0..11
    int jt = (xcd >> 2) * 8 + (ii & 7); // 0..15
    int iBase = it << 8, jBase = jt << 8;

    int w = t >> 6, lane = t & 63;
    int lr = lane & 15, lh = lane >> 4;
    int wm = w >> 2, wn = w & 3; // 2m x 4n waves

    int srow = t >> 3;             // 0..63
    int scbx = ((t & 7) << 4) ^ ((srow & 7) << 4);

    const char* Ab = (const char*)Wcat;
    const char* Bb = (const char*)Xb;

    floatx4 acc[8][4];
#pragma unroll
    for (int i = 0; i < 8; i++)
#pragma unroll
        for (int j = 0; j < 4; j++) acc[i][j] = (floatx4){0.f, 0.f, 0.f, 0.f};

    auto stageA = [&](int buf, int kt) {
        int k0b = kt << 7;
#pragma unroll
        for (int c = 0; c < 4; c++)
            gl2lds16(Ab + (size_t)(iBase + c * 64 + srow) * 2048 + k0b + scbx,
                     &lds[buf][0][c * 8192 + t * 16]);
    };
    auto stageB = [&](int buf, int kt) {
        int k0b = kt << 7;
#pragma unroll
        for (int c = 0; c < 4; c++)
            gl2lds16(Bb + (size_t)(jBase + c * 64 + srow) * 2048 + k0b + scbx,
                     &lds[buf][1][c * 8192 + t * 16]);
    };

    short8 af[4][2], bf[4][2];
    auto rdA = [&](int buf, int qm) {
#pragma unroll
        for (int mi = 0; mi < 4; mi++)
#pragma unroll
            for (int ks = 0; ks < 2; ks++) {
                int row = wm * 128 + qm * 64 + mi * 16 + lr;
                af[mi][ks] = *reinterpret_cast<const short8*>(
                    &lds[buf][0][(row * 128 + ks * 64 + lh * 16) ^ ((row & 7) << 4)]);
            }
    };
    auto rdB = [&](int buf, int qn) {
#pragma unroll
        for (int ni = 0; ni < 2; ni++)
#pragma unroll
            for (int ks = 0; ks < 2; ks++) {
                int row = wn * 64 + qn * 32 + ni * 16 + lr;
                bf[qn * 2 + ni][ks] = *reinterpret_cast<const short8*>(
                    &lds[buf][1][(row * 128 + ks * 64 + lh * 16) ^ ((row & 7) << 4)]);
            }
    };
    auto mfma16 = [&](int qm, int qn) {
        __builtin_amdgcn_s_setprio(1);
#pragma unroll
        for (int mi = 0; mi < 4; mi++)
#pragma unroll
            for (int ni = 0; ni < 2; ni++)
#pragma unroll
                for (int ks = 0; ks < 2; ks++)
                    acc[qm * 4 + mi][qn * 2 + ni] = __builtin_amdgcn_mfma_f32_16x16x32_bf16(
                        af[mi][ks], bf[qn * 2 + ni][ks], acc[qm * 4 + mi][qn * 2 + ni], 0, 0, 0);
        __builtin_amdgcn_s_setprio(0);
    };

    const int NT = 16; // K=1024 / 64
    stageA(0, 0);
    stageB(0, 0);
    WAIT_VM0();
    __builtin_amdgcn_s_barrier();

    for (int kt = 0; kt < NT; ++kt) {
        int cur = kt & 1, nxt = cur ^ 1;
        bool pf = (kt + 1 < NT);
        // ---- phase 0: quadrant (0,0); prefetch next A ----
        rdA(cur, 0);
        rdB(cur, 0);
        if (pf) stageA(nxt, kt + 1);
        __builtin_amdgcn_s_barrier();
        WAIT_LGKM0();
        __builtin_amdgcn_sched_barrier(0);
        mfma16(0, 0);
        __builtin_amdgcn_s_barrier();
        // ---- phase 1: quadrant (0,1); prefetch next B ----
        rdB(cur, 1);
        if (pf) stageB(nxt, kt + 1);
        __builtin_amdgcn_s_barrier();
        WAIT_LGKM0();
        __builtin_amdgcn_sched_barrier(0);
        mfma16(0, 1);
        __builtin_amdgcn_s_barrier();
        // ---- phase 2: quadrant (1,0) ----
        rdA(cur, 1);
        __builtin_amdgcn_s_barrier();
        WAIT_LGKM0();
        __builtin_amdgcn_sched_barrier(0);
        mfma16(1, 0);
        __builtin_amdgcn_s_barrier();
        // ---- phase 3: quadrant (1,1); drain prefetch before next-iter reads ----
        if (pf) WAIT_VM0();
        __builtin_amdgcn_s_barrier();
        mfma16(1, 1);
        __builtin_amdgcn_s_barrier();
    }

    // ---------------- epilogue ----------------
    int wsel = iBase >> 10;
    const float* bias = (wsel == 0) ? bq : (wsel == 1) ? bk : bv;
    __syncthreads(); // LDS free for reuse

    if (wsel < 2) {
        unsigned short* O = wsel ? Kg : Qg;
        float scale = wsel ? 1.0f : QSCALE;
#pragma unroll
        for (int mi8 = 0; mi8 < 8; mi8++) {
            int i = iBase + wm * 128 + mi8 * 16 + lh * 4;
            int im = i & 1023;
            int h = im >> 6, d0 = im & 63;
            float4 bs = *reinterpret_cast<const float4*>(&bias[im]);
#pragma unroll
            for (int nf = 0; nf < 4; nf++) {
                int j = jBase + wn * 64 + nf * 16 + lr;
                int b_ = j >> 11, s = j & (S_LEN - 1);
                ushort4 pk;
                pk.x = f2bf((acc[mi8][nf][0] + bs.x) * scale);
                pk.y = f2bf((acc[mi8][nf][1] + bs.y) * scale);
                pk.z = f2bf((acc[mi8][nf][2] + bs.z) * scale);
                pk.w = f2bf((acc[mi8][nf][3] + bs.w) * scale);
                *reinterpret_cast<ushort4*>(
                    &O[((size_t)(b_ * NH + h) * S_LEN + s) * DH + d0]) = pk;
            }
        }
    } else {
        // V: transpose each wave's 128x64 slab through LDS -> [b][h][d][s] coalesced
        char* lw = &lds[0][0][0] + w * 16384;
#pragma unroll
        for (int mi8 = 0; mi8 < 8; mi8++) {
            int i = iBase + wm * 128 + mi8 * 16 + lh * 4;
            float4 bs = *reinterpret_cast<const float4*>(&bias[i & 1023]);
#pragma unroll
            for (int nf = 0; nf < 4; nf++) {
                int jl = nf * 16 + lr;
#pragma unroll
                for (int r = 0; r < 4; r++) {
                    int il = mi8 * 16 + lh * 4 + r;
                    float bb = (r == 0) ? bs.x : (r == 1) ? bs.y : (r == 2) ? bs.z : bs.w;
                    *reinterpret_cast<unsigned short*>(
                        lw + ((il * 128 + jl * 2) ^ ((il & 7) << 4))) =
                        f2bf(acc[mi8][nf][r] + bb);
                }
            }
        }
        __syncthreads();
#pragma unroll
        for (int rep = 0; rep < 16; rep++) {
            int idx = rep * 64 + lane;
            int il = idx >> 3, jb = idx & 7;
            short8 vv = *reinterpret_cast<const short8*>(
                lw + ((il * 128 + jb * 16) ^ ((il & 7) << 4)));
            int i = iBase + wm * 128 + il;
            int im = i & 1023;
            int h = im >> 6, d = im & 63;
            int j = jBase + wn * 64 + jb * 8;
            int b_ = j >> 11, s = j & (S_LEN - 1);
            *reinterpret_cast<short8*>(
                &Vtg[((size_t)(b_ * NH + h) * DH + d) * S_LEN + s]) = vv;
        }
    }
}

// ---------------- output projection: 8-phase counted-vmcnt, 128x128, C^T ------------
// out[j=token][i=feature] = sum_k Og[j][k] * Wot_t[i][k] + bo[i].
// Grid 256 (8 i-tiles x 32 j-tiles) = 1 block/CU, 512 thr / 8 waves (2m x 4n,
// wave 64x32). 2 phases per K-step, vmcnt(0) once per K-step (loads span barriers).
__global__ __launch_bounds__(512, 2) void gemm_o8(const unsigned short* __restrict__ Wot,
                                                  const unsigned short* __restrict__ Og,
                                                  const float* __restrict__ bo,
                                                  float* __restrict__ out) {
    __shared__ __align__(16) char lds[2][2][16384]; // [buf][A=0/B=1][128 rows x 128B]

    int t = threadIdx.x;
    int b = blockIdx.x;
    int xcd = b & 7, ii = b >> 3;       // ii in [0,32)
    int it = ii & 7;                    // all 8 i-tiles per XCD (Wot 2MB)
    int jt = (xcd << 2) | (ii >> 3);    // 4 j-tiles per XCD (Og 1MB)
    int iBase = it << 7, jBase = jt << 7;

    int w = t >> 6, lane = t & 63;
    int lr = lane & 15, lh = lane >> 4;
    int wm = w >> 2, wn = w & 3; // 2m x 4n

    int srow = t >> 3; // 0..63
    int scbx = ((t & 7) << 4) ^ ((srow & 7) << 4);

    const char* Ab = (const char*)Wot;
    const char* Bb = (const char*)Og;

    floatx4 acc[4][2];
#pragma unroll
    for (int i = 0; i < 4; i++)
#pragma unroll
        for (int j = 0; j < 2; j++) acc[i][j] = (floatx4){0.f, 0.f, 0.f, 0.f};

    auto stageA = [&](int buf, int kt) {
        int k0b = kt << 7;
#pragma unroll
        for (int c = 0; c < 2; c++)
            gl2lds16(Ab + (size_t)(iBase + c * 64 + srow) * 2048 + k0b + scbx,
                     &lds[buf][0][c * 8192 + t * 16]);
    };
    auto stageB = [&](int buf, int kt) {
        int k0b = kt << 7;
#pragma unroll
        for (int c = 0; c < 2; c++)
            gl2lds16(Bb + (size_t)(jBase + c * 64 + srow) * 2048 + k0b + scbx,
                     &lds[buf][1][c * 8192 + t * 16]);
    };

    short8 af[4][2], bf[2][2];
    auto rdA = [&](int buf, int qm) {
#pragma unroll
        for (int m2 = 0; m2 < 2; m2++)
#pragma unroll
            for (int ks = 0; ks < 2; ks++) {
                int mi = qm * 2 + m2;
                int row = wm * 64 + mi * 16 + lr;
                af[mi][ks] = *reinterpret_cast<const short8*>(
                    &lds[buf][0][(row * 128 + ks * 64 + lh * 16) ^ ((row & 7) << 4)]);
            }
    };
    auto rdB = [&](int buf) {
#pragma unroll
        for (int nf = 0; nf < 2; nf++)
#pragma unroll
            for (int ks = 0; ks < 2; ks++) {
                int row = wn * 32 + nf * 16 + lr;
                bf[nf][ks] = *reinterpret_cast<const short8*>(
                    &lds[buf][1][(row * 128 + ks * 64 + lh * 16) ^ ((row & 7) << 4)]);
            }
    };
    auto mfma8 = [&](int qm) {
        __builtin_amdgcn_s_setprio(1);
#pragma unroll
        for (int m2 = 0; m2 < 2; m2++)
#pragma unroll
            for (int nf = 0; nf < 2; nf++)
#pragma unroll
                for (int ks = 0; ks < 2; ks++) {
                    int mi = qm * 2 + m2;
                    acc[mi][nf] = __builtin_amdgcn_mfma_f32_16x16x32_bf16(
                        af[mi][ks], bf[nf][ks], acc[mi][nf], 0, 0, 0);
                }
        __builtin_amdgcn_s_setprio(0);
    };

    const int NT = 16; // K=1024 / 64
    stageA(0, 0);
    stageB(0, 0);
    WAIT_VM0();
    __builtin_amdgcn_s_barrier();

    for (int kt = 0; kt < NT; ++kt) {
        int cur = kt & 1, nxt = cur ^ 1;
        bool pf = (kt + 1 < NT);
        // ---- phase 0: A-quadrant 0 + both B; prefetch next A ----
        rdA(cur, 0);
        rdB(cur);
        if (pf) stageA(nxt, kt + 1);
        __builtin_amdgcn_s_barrier();
        WAIT_LGKM0();
        __builtin_amdgcn_sched_barrier(0);
        mfma8(0);
        __builtin_amdgcn_s_barrier();
        // ---- phase 1: A-quadrant 1; prefetch next B; drain once per K-step ----
        rdA(cur, 1);
        if (pf) stageB(nxt, kt + 1);
        __builtin_amdgcn_s_barrier();
        WAIT_LGKM0();
        __builtin_amdgcn_sched_barrier(0);
        mfma8(1);
        if (pf) WAIT_VM0();
        __builtin_amdgcn_s_barrier();
    }

    // ---- epilogue: lane holds 4 consecutive features -> float4 stores ----
#pragma unroll
    for (int mi = 0; mi < 4; mi++) {
        int i = iBase + wm * 64 + mi * 16 + lh * 4;
        float4 bs = *reinterpret_cast<const float4*>(&bo[i]);
#pragma unroll
        for (int nf = 0; nf < 2; nf++) {
            int j = jBase + wn * 32 + nf * 16 + lr;
            float4 o;
            o.x = acc[mi][nf][0] + bs.x;
            o.y = acc[mi][nf][1] + bs.y;
            o.z = acc[mi][nf][2] + bs.z;
            o.w = acc[mi][nf][3] + bs.w;
            *reinterpret_cast<float4*>(&out[(size_t)j * E_DIM + i]) = o;
        }
    }
}

// ---------------- causal flash attention: swapped QK^T, in-register P ---------------
// (round-10 version: 32KB LDS, 4 blocks/CU, 960-block balanced KV-split)
__global__ __launch_bounds__(256, 4) void attn_fwd(const unsigned short* __restrict__ Qg,
                                                   const unsigned short* __restrict__ Kg,
                                                   const unsigned short* __restrict__ Vtg,
                                                   unsigned short* __restrict__ Og,
                                                   unsigned short* __restrict__ Opart,
                                                   float* __restrict__ lpart) {
    __shared__ __align__(16) char kt_lds[2][KVB * 128];
    __shared__ __align__(16) char vt_lds[2][KVB * 128];

    int bid = blockIdx.x;
    int xcd = bid & 7, ii = bid >> 3;  // [0,120)
    int bh = (xcd << 2) + ii / 30;
    int jj = 29 - (ii % 30);           // dispatch big-qb chunks first
    int qb, ch, c;
    if (jj < 6)        { qb = jj; ch = 0; c = 1; }
    else if (jj < 18)  { int u = jj - 6;  qb = 6 + (u >> 1); ch = u & 1; c = 2; }
    else               { int u = jj - 18; qb = 12 + u / 3;   ch = u % 3; c = 3; }
    int T = 2 * qb + 2;
    int kt_lo = ch * T / c;
    int kt_hi = (ch + 1) * T / c - 1;
    bool split = (c > 1);

    int w = threadIdx.x >> 6, lane = threadIdx.x & 63;
    int lr = lane & 15, lh = lane >> 4;
    int q0 = qb * QB + w * 32;

    const char* Kb = (const char*)(Kg + (size_t)bh * S_LEN * DH);
    const char* Vb = (const char*)(Vtg + (size_t)bh * DH * S_LEN);
    const unsigned short* Qb = Qg + (size_t)bh * S_LEN * DH;

    int wi0 = w * 2;
    int srow0 = wi0 * 8 + (lane >> 3);
    int scol = (lane & 7) << 4;

    auto stage = [&](int buf, int kt) { // K + V tiles, 2+2 x 1KB per wave
        int kv0 = kt * KVB;
#pragma unroll
        for (int i = 0; i < 2; ++i) {
            int row = srow0 + i * 8;
            int colb = scol ^ ((row & 7) << 4);
            gl2lds16(Kb + (size_t)(kv0 + row) * 128 + colb,
                     kt_lds[buf] + (wi0 + i) * 1024);
            gl2lds16(Vb + (size_t)row * (S_LEN * 2) + (size_t)kv0 * 2 + colb,
                     vt_lds[buf] + (wi0 + i) * 1024);
        }
    };

    short8 aq[2][2];
#pragma unroll
    for (int m = 0; m < 2; m++)
#pragma unroll
        for (int ks = 0; ks < 2; ks++)
            aq[m][ks] = *reinterpret_cast<const short8*>(
                Qb + (size_t)(q0 + m * 16 + lr) * DH + ks * 32 + lh * 8);

    floatx4 oacc[2][4];
    float lsum[2];
#pragma unroll
    for (int m = 0; m < 2; m++) {
#pragma unroll
        for (int dt = 0; dt < 4; dt++) oacc[m][dt] = (floatx4){0.f, 0.f, 0.f, 0.f};
        lsum[m] = 0.f;
    }

    stage(0, kt_lo);
    __syncthreads();
    int buf = 0;

    for (int kt = kt_lo; kt <= kt_hi; ++kt) {
        if (kt < kt_hi) stage(buf ^ 1, kt + 1);
        int kv0 = kt * KVB;
        bool skip = (kv0 > q0 + 31);
        if (!skip) {
            const char* Kt = kt_lds[buf];
            const char* Vt = vt_lds[buf];
            // ---- QK^T (swapped: A=K, B=Q) -> S^T: lane holds q=lr, k=16nt+4lh+r ----
            floatx4 sacc[2][4];
#pragma unroll
            for (int m = 0; m < 2; m++)
#pragma unroll
                for (int nt = 0; nt < 4; nt++) sacc[m][nt] = (floatx4){0.f, 0.f, 0.f, 0.f};
#pragma unroll
            for (int ks = 0; ks < 2; ks++)
#pragma unroll
                for (int nt = 0; nt < 4; nt++) {
                    int row = nt * 16 + lr;
                    int addr = (row * 128 + ks * 64 + lh * 16) ^ ((row & 7) << 4);
                    short8 bk = *reinterpret_cast<const short8*>(Kt + addr);
#pragma unroll
                    for (int m = 0; m < 2; m++)
                        sacc[m][nt] = __builtin_amdgcn_mfma_f32_16x16x32_bf16(
                            bk, aq[m][ks], sacc[m][nt], 0, 0, 0);
                }
            // ---- causal mask (diagonal band only): kv = kv0+16nt+4lh+r, q = q0+16m+lr
            if (kv0 + KVB - 1 > q0) {
#pragma unroll
                for (int m = 0; m < 2; m++)
#pragma unroll
                    for (int nt = 0; nt < 4; nt++)
#pragma unroll
                        for (int r = 0; r < 4; r++) {
                            int kcol = kv0 + nt * 16 + lh * 4 + r;
                            int qrow = q0 + m * 16 + lr;
                            if (kcol > qrow) sacc[m][nt][r] = -1e30f;
                        }
            }
            // ---- P = 2^S (lane-local rows), pack to bf16 pairs ----
            unsigned int pk[2][4][2];
#pragma unroll
            for (int m = 0; m < 2; m++) {
                float ls = 0.f;
#pragma unroll
                for (int nt = 0; nt < 4; nt++) {
#pragma unroll
                    for (int r = 0; r < 4; r++) {
                        float p = __builtin_amdgcn_exp2f(sacc[m][nt][r]);
                        sacc[m][nt][r] = p;
                        ls += p;
                    }
                    pk[m][nt][0] = pack2bf(sacc[m][nt][0], sacc[m][nt][1]);
                    pk[m][nt][1] = pack2bf(sacc[m][nt][2], sacc[m][nt][3]);
                }
                lsum[m] += ls;
            }
            // ---- exchange: build A-frag P[q=lr][k=32ks+8lh+e] from pk ----
            short8 pa[2][2];
            int hsel = lh >> 1;
#pragma unroll
            for (int m = 0; m < 2; m++)
#pragma unroll
                for (int ks = 0; ks < 2; ks++) {
                    intx4 u;
#pragma unroll
                    for (int t4 = 0; t4 < 4; t4++) {
                        int src = lr + 32 * (lh & 1) + 16 * (t4 >> 1);
                        int r0 = __shfl((int)pk[m][2 * ks][t4 & 1], src);
                        int r1 = __shfl((int)pk[m][2 * ks + 1][t4 & 1], src);
                        u[t4] = hsel ? r1 : r0;
                    }
                    pa[m][ks] = __builtin_bit_cast(short8, u);
                }
            // ---- PV (O row=q=4lh+r, col=d=lr) ----
#pragma unroll
            for (int ks = 0; ks < 2; ks++)
#pragma unroll
                for (int dt = 0; dt < 4; dt++) {
                    int row = dt * 16 + lr;
                    int addr = (row * 128 + ks * 64 + lh * 16) ^ ((row & 7) << 4);
                    short8 bv = *reinterpret_cast<const short8*>(Vt + addr);
#pragma unroll
                    for (int m = 0; m < 2; m++)
                        oacc[m][dt] = __builtin_amdgcn_mfma_f32_16x16x32_bf16(
                            pa[m][ks], bv, oacc[m][dt], 0, 0, 0);
                }
        }
        __syncthreads(); // drains this iter's stage + readers done with `buf`
        buf ^= 1;
    }

    // lsum[m] lives per q=lr, partial over lh: reduce across the 4 lh groups
#pragma unroll
    for (int m = 0; m < 2; m++) {
        lsum[m] += __shfl_xor(lsum[m], 16);
        lsum[m] += __shfl_xor(lsum[m], 32);
    }

    if (split) {
        int base = (qb < 12) ? (qb - 6) * 2 : 12 + (qb - 12) * 3;
        int pi = bh * 24 + base + ch;
        unsigned short* Op = Opart + (size_t)pi * (QB * DH);
        float* lp = lpart + (size_t)pi * QB;
#pragma unroll
        for (int m = 0; m < 2; m++) {
            if (lh == 0) lp[w * 32 + m * 16 + lr] = lsum[m];
#pragma unroll
            for (int r = 0; r < 4; r++) {
                int row = w * 32 + m * 16 + lh * 4 + r;
#pragma unroll
                for (int dt = 0; dt < 4; dt++)
                    Op[row * DH + dt * 16 + lr] = f2bf(oacc[m][dt][r]);
            }
        }
    } else {
        int b_ = bh >> 4, h_ = bh & 15;
#pragma unroll
        for (int m = 0; m < 2; m++) {
#pragma unroll
            for (int r = 0; r < 4; r++) {
                float lv = __shfl(lsum[m], lh * 4 + r); // lsum of q-row lh*4+r
                float inv = 1.f / lv;
                int srow = q0 + m * 16 + lh * 4 + r;
#pragma unroll
                for (int dt = 0; dt < 4; dt++)
                    Og[((size_t)b_ * S_LEN + srow) * E_DIM + h_ * 64 + dt * 16 + lr] =
                        f2bf(oacc[m][dt][r] * inv);
            }
        }
    }
}

// ---------------- merge KV-split partials (2 or 3 chunks), normalize, write Og ------
__global__ __launch_bounds__(256) void attn_reduce(const unsigned short* __restrict__ Opart,
                                                   const float* __restrict__ lpart,
                                                   unsigned short* __restrict__ Og) {
    int bh = blockIdx.x;      // 0..31
    int qb = 6 + blockIdx.y;  // 6..15
    int c = (qb < 12) ? 2 : 3;
    int base = (qb < 12) ? (qb - 6) * 2 : 12 + (qb - 12) * 3;
    int pi0 = bh * 24 + base;
    const unsigned short* P0 = Opart + (size_t)pi0 * (QB * DH);
    const float* l0 = lpart + (size_t)pi0 * QB;
    int t = threadIdx.x;
    int cg = t & 7, r0 = t >> 3;
    int b_ = bh >> 4, h_ = bh & 15;
    int qrow0 = qb * QB;
#pragma unroll
    for (int rr = 0; rr < 4; rr++) {
        int row = r0 + rr * 32;
        float ls = l0[row] + l0[QB + row];
        if (c == 3) ls += l0[2 * QB + row];
        float inv = 1.f / ls;
        short8 v0 = *reinterpret_cast<const short8*>(P0 + row * DH + cg * 8);
        short8 v1 = *reinterpret_cast<const short8*>(P0 + QB * DH + row * DH + cg * 8);
        float s[8];
#pragma unroll
        for (int j = 0; j < 8; j++)
            s[j] = bf2f((unsigned short)v0[j]) + bf2f((unsigned short)v1[j]);
        if (c == 3) {
            short8 v2 = *reinterpret_cast<const short8*>(P0 + 2 * QB * DH + row * DH + cg * 8);
#pragma unroll
            for (int j = 0; j < 8; j++) s[j] += bf2f((unsigned short)v2[j]);
        }
        short8 o;
#pragma unroll
        for (int j = 0; j < 8; j++) o[j] = (short)f2bf(s[j] * inv);
        *reinterpret_cast<short8*>(Og + ((size_t)b_ * S_LEN + qrow0 + row) * E_DIM +
                                   h_ * 64 + cg * 8) = o;
    }
}

extern "C" void kernel_launch(void* const* d_in, const int* in_sizes, int n_in,
                              void* d_out, int out_size, void* d_ws, size_t ws_size,
                              hipStream_t stream) {
    const float* x  = (const float*)d_in[0];
    const float* Wq = (const float*)d_in[1];
    const float* bq = (const float*)d_in[2];
    const float* Wk = (const float*)d_in[3];
    const float* bk = (const float*)d_in[4];
    const float* Wv = (const float*)d_in[5];
    const float* bv = (const float*)d_in[6];
    const float* Wo = (const float*)d_in[7];
    const float* bo = (const float*)d_in[8];
    float* out = (float*)d_out;

    const size_t NX = (size_t)M_ROWS * E_DIM; // 4M elems
    const size_t NW = (size_t)E_DIM * E_DIM;  // 1M elems
    unsigned short* ws  = (unsigned short*)d_ws;
    unsigned short* Xb  = ws;
    unsigned short* Wqt = Xb + NX;   // Wqt|Wkt|Wvt contiguous = Wcat [3072][1024]
    unsigned short* Wkt = Wqt + NW;
    unsigned short* Wvt = Wkt + NW;
    unsigned short* Wot = Wvt + NW;
    unsigned short* Qg  = Wot + NW;
    unsigned short* Kg  = Qg + NX;
    unsigned short* Vtg = Kg + NX;
    unsigned short* Og  = Vtg + NX;
    // Partials OVERLAY the Xb/Wqt/Wkt/Wvt region (dead after gemm_qkv8):
    // 32 bh * 24 slots * 8192 u16 = 12.6 MB + lpart 393KB  <  14 MB (Xb..Wvt)
    unsigned short* Opart = Xb;
    float* lpart = (float*)(Opart + (size_t)32 * 24 * QB * DH);

    prep<<<dim3(8192), 256, 0, stream>>>(x, Xb, Wq, Wk, Wv, Wo, Wqt, Wkt, Wvt, Wot);

    gemm_qkv8<<<dim3(192), 512, 0, stream>>>(Wqt, Xb, bq, bk, bv, Qg, Kg, Vtg);

    attn_fwd<<<dim3(960), 256, 0, stream>>>(Qg, Kg, Vtg, Og, Opart, lpart);
    attn_reduce<<<dim3(B_SZ * NH, 10), 256, 0, stream>>>(Opart, lpart, Og);

    gemm_o8<<<dim3(256), 512, 0, stream>>>(Wot, Og, bo, out);
}

// Round 14
// 107.079 us; speedup vs baseline: 1.1740x; 1.0633x over previous
//
#include <hip/hip_runtime.h>
#include <hip/hip_bf16.h>

#define B_SZ 2
#define S_LEN 2048
#define E_DIM 1024
#define NH 16
#define DH 64
#define M_ROWS (B_SZ * S_LEN) /* 4096 */
#define QB 128
#define KVB 64

typedef __attribute__((ext_vector_type(8))) short short8;
typedef __attribute__((ext_vector_type(4))) float floatx4;
typedef __attribute__((ext_vector_type(4))) int intx4;

static __device__ __forceinline__ unsigned short f2bf(float f) {
    __hip_bfloat16 h = __float2bfloat16(f);
    return *reinterpret_cast<unsigned short*>(&h);
}
static __device__ __forceinline__ float bf2f(unsigned short u) {
    unsigned int v = ((unsigned int)u) << 16;
    return __builtin_bit_cast(float, v);
}
static __device__ __forceinline__ unsigned int pack2bf(float lo, float hi) {
    return (unsigned int)f2bf(lo) | ((unsigned int)f2bf(hi) << 16);
}

static __device__ __forceinline__ void gl2lds16(const void* g, void* l) {
    __builtin_amdgcn_global_load_lds((const __attribute__((address_space(1))) void*)g,
                                     (__attribute__((address_space(3))) void*)l, 16, 0, 0);
}

#define WAIT_VM0() asm volatile("s_waitcnt vmcnt(0)" ::: "memory")
#define WAIT_LGKM0() asm volatile("s_waitcnt lgkmcnt(0)" ::: "memory")

// ---------------- prep: fp32->bf16 convert (x) + 4 weight transposes, fused --------
__global__ __launch_bounds__(256) void prep(const float* __restrict__ x,
                                            unsigned short* __restrict__ Xb,
                                            const float* __restrict__ W0,
                                            const float* __restrict__ W1,
                                            const float* __restrict__ W2,
                                            const float* __restrict__ W3,
                                            unsigned short* __restrict__ T0,
                                            unsigned short* __restrict__ T1,
                                            unsigned short* __restrict__ T2,
                                            unsigned short* __restrict__ T3) {
    __shared__ float tile[32][33];
    int bid = blockIdx.x;
    int t = threadIdx.x;
    if (bid < 4096) { // cvt: 4096 blocks x 1024 elems
        int i = (bid * 256 + t) * 4;
        float4 v = *reinterpret_cast<const float4*>(x + i);
        ushort4 o;
        o.x = f2bf(v.x); o.y = f2bf(v.y); o.z = f2bf(v.z); o.w = f2bf(v.w);
        *reinterpret_cast<ushort4*>(Xb + i) = o;
        return;
    }
    int u = bid - 4096;
    int z = u >> 10, rest = u & 1023;
    int bx = (rest & 31) * 32, by = (rest >> 5) * 32;
    const float* W = (z == 0) ? W0 : (z == 1) ? W1 : (z == 2) ? W2 : W3;
    unsigned short* Wt = (z == 0) ? T0 : (z == 1) ? T1 : (z == 2) ? T2 : T3;
    int tx = t & 31, ty = t >> 5; // 32 x 8
#pragma unroll
    for (int i = 0; i < 32; i += 8)
        tile[ty + i][tx] = W[(size_t)(by + ty + i) * E_DIM + bx + tx];
    __syncthreads();
#pragma unroll
    for (int i = 0; i < 32; i += 8)
        Wt[(size_t)(bx + ty + i) * E_DIM + by + tx] = f2bf(tile[tx][ty + i]);
}

// Q scale folds 1/sqrt(D) AND log2(e) so attention can use raw v_exp_f32 (2^x).
#define QSCALE 0.18033688011112042f

// ---------------- fused QKV projection: 4-phase counted-vmcnt, 192x256 tiles --------
// C[i=feature][j=token] = sum_k Wcat[i][k] * Xb[j][k].  16 i-tiles x 16 j-tiles =
// 256 blocks = exactly 1/CU (100% coverage; the old 256x256 grid of 192 left 64 CUs
// idle). 512 thr / 8 waves (2m x 4n), per-wave 96x64 (6x4 frags), LDS 112KB dbuf.
__global__ __launch_bounds__(512, 1) void gemm_qkv8(const unsigned short* __restrict__ Wcat,
                                                    const unsigned short* __restrict__ Xb,
                                                    const float* __restrict__ bq,
                                                    const float* __restrict__ bk,
                                                    const float* __restrict__ bv,
                                                    unsigned short* __restrict__ Qg,
                                                    unsigned short* __restrict__ Kg,
                                                    unsigned short* __restrict__ Vtg) {
    __shared__ __align__(16) char lds[2][57344]; // per buf: A 192x128B | B 256x128B

    int t = threadIdx.x;
    int b = blockIdx.x;
    int xcd = b & 7, ii = b >> 3;        // ii in [0,32)
    int it = (xcd & 3) * 4 + (ii >> 3);  // 0..15
    int jt = (xcd >> 2) * 8 + (ii & 7);  // 0..15
    int iBase = it * 192, jBase = jt << 8;

    int w = t >> 6, lane = t & 63;
    int lr = lane & 15, lh = lane >> 4;
    int wm = w >> 2, wn = w & 3; // 2m x 4n waves

    int srow = t >> 3;             // 0..63
    int scbx = ((t & 7) << 4) ^ ((srow & 7) << 4);

    const char* Ab = (const char*)Wcat;
    const char* Bb = (const char*)Xb;

    floatx4 acc[6][4];
#pragma unroll
    for (int i = 0; i < 6; i++)
#pragma unroll
        for (int j = 0; j < 4; j++) acc[i][j] = (floatx4){0.f, 0.f, 0.f, 0.f};

    auto stageA = [&](int buf, int kt) { // 192 rows = 3 passes
        int k0b = kt << 7;
#pragma unroll
        for (int c = 0; c < 3; c++)
            gl2lds16(Ab + (size_t)(iBase + c * 64 + srow) * 2048 + k0b + scbx,
                     &lds[buf][c * 8192 + t * 16]);
    };
    auto stageB = [&](int buf, int kt) { // 256 rows = 4 passes
        int k0b = kt << 7;
#pragma unroll
        for (int c = 0; c < 4; c++)
            gl2lds16(Bb + (size_t)(jBase + c * 64 + srow) * 2048 + k0b + scbx,
                     &lds[buf][24576 + c * 8192 + t * 16]);
    };

    short8 af[3][2], bf[4][2];
    auto rdA = [&](int buf, int qm) { // 3 m-frags of the qm half
#pragma unroll
        for (int ml = 0; ml < 3; ml++)
#pragma unroll
            for (int ks = 0; ks < 2; ks++) {
                int row = wm * 96 + (qm * 3 + ml) * 16 + lr;
                af[ml][ks] = *reinterpret_cast<const short8*>(
                    &lds[buf][(row * 128 + ks * 64 + lh * 16) ^ ((row & 7) << 4)]);
            }
    };
    auto rdB = [&](int buf, int qn) { // 2 n-frags of the qn half
#pragma unroll
        for (int nl = 0; nl < 2; nl++)
#pragma unroll
            for (int ks = 0; ks < 2; ks++) {
                int row = wn * 64 + (qn * 2 + nl) * 16 + lr;
                bf[qn * 2 + nl][ks] = *reinterpret_cast<const short8*>(
                    &lds[buf][24576 + ((row * 128 + ks * 64 + lh * 16) ^ ((row & 7) << 4))]);
            }
    };
    auto mfma12 = [&](int qm, int qn) {
        __builtin_amdgcn_s_setprio(1);
#pragma unroll
        for (int ml = 0; ml < 3; ml++)
#pragma unroll
            for (int nl = 0; nl < 2; nl++)
#pragma unroll
                for (int ks = 0; ks < 2; ks++)
                    acc[qm * 3 + ml][qn * 2 + nl] = __builtin_amdgcn_mfma_f32_16x16x32_bf16(
                        af[ml][ks], bf[qn * 2 + nl][ks], acc[qm * 3 + ml][qn * 2 + nl], 0, 0, 0);
        __builtin_amdgcn_s_setprio(0);
    };

    const int NT = 16; // K=1024 / 64
    stageA(0, 0);
    stageB(0, 0);
    WAIT_VM0();
    __builtin_amdgcn_s_barrier();

    for (int kt = 0; kt < NT; ++kt) {
        int cur = kt & 1, nxt = cur ^ 1;
        bool pf = (kt + 1 < NT);
        // ---- phase 0: (qm0,qn0); prefetch next A ----
        rdA(cur, 0);
        rdB(cur, 0);
        if (pf) stageA(nxt, kt + 1);
        __builtin_amdgcn_s_barrier();
        WAIT_LGKM0();
        __builtin_amdgcn_sched_barrier(0);
        mfma12(0, 0);
        __builtin_amdgcn_s_barrier();
        // ---- phase 1: (qm0,qn1); prefetch next B ----
        rdB(cur, 1);
        if (pf) stageB(nxt, kt + 1);
        __builtin_amdgcn_s_barrier();
        WAIT_LGKM0();
        __builtin_amdgcn_sched_barrier(0);
        mfma12(0, 1);
        __builtin_amdgcn_s_barrier();
        // ---- phase 2: (qm1,qn0) ----
        rdA(cur, 1);
        __builtin_amdgcn_s_barrier();
        WAIT_LGKM0();
        __builtin_amdgcn_sched_barrier(0);
        mfma12(1, 0);
        __builtin_amdgcn_s_barrier();
        // ---- phase 3: (qm1,qn1); drain prefetch once per K-step ----
        if (pf) WAIT_VM0();
        __builtin_amdgcn_s_barrier();
        mfma12(1, 1);
        __builtin_amdgcn_s_barrier();
    }

    // ---------------- epilogue: per-m-frag (wsel uniform per 16-feature frag) -------
    __syncthreads(); // LDS free for reuse
    unsigned short* vt = reinterpret_cast<unsigned short*>(&lds[0][0] + w * 2560); // [16][80]

#pragma unroll
    for (int mi = 0; mi < 6; mi++) {
        int i0 = iBase + wm * 96 + mi * 16;
        int wsel = i0 >> 10;
        int im = i0 & 1023;
        const float* bias = (wsel == 0) ? bq : (wsel == 1) ? bk : bv;
        float4 bs = *reinterpret_cast<const float4*>(&bias[im + lh * 4]);
        if (wsel < 2) {
            // Q/K: lane holds 4 consecutive features at one token -> ushort4
            unsigned short* O = wsel ? Kg : Qg;
            float scale = wsel ? 1.0f : QSCALE;
            int h = im >> 6, d0 = (im & 63) + lh * 4;
#pragma unroll
            for (int nf = 0; nf < 4; nf++) {
                int j = jBase + wn * 64 + nf * 16 + lr;
                int b_ = j >> 11, s = j & (S_LEN - 1);
                ushort4 pk;
                pk.x = f2bf((acc[mi][nf][0] + bs.x) * scale);
                pk.y = f2bf((acc[mi][nf][1] + bs.y) * scale);
                pk.z = f2bf((acc[mi][nf][2] + bs.z) * scale);
                pk.w = f2bf((acc[mi][nf][3] + bs.w) * scale);
                *reinterpret_cast<ushort4*>(
                    &O[((size_t)(b_ * NH + h) * S_LEN + s) * DH + d0]) = pk;
            }
        } else {
            // V: transpose 16 features x 64 tokens through wave-private LDS tile
#pragma unroll
            for (int nf = 0; nf < 4; nf++)
#pragma unroll
                for (int r = 0; r < 4; r++) {
                    float bb = (r == 0) ? bs.x : (r == 1) ? bs.y : (r == 2) ? bs.z : bs.w;
                    vt[(lh * 4 + r) * 80 + nf * 16 + lr] = f2bf(acc[mi][nf][r] + bb);
                }
            WAIT_LGKM0();
            __builtin_amdgcn_sched_barrier(0);
            int h = im >> 6, d0 = im & 63;
#pragma unroll
            for (int p = 0; p < 2; p++) {
                int idx = p * 64 + lane;
                int dl = idx >> 3, sg = idx & 7;
                short8 vv = *reinterpret_cast<const short8*>(&vt[dl * 80 + sg * 8]);
                int j = jBase + wn * 64 + sg * 8;
                int b_ = j >> 11, s = j & (S_LEN - 1);
                *reinterpret_cast<short8*>(
                    &Vtg[((size_t)(b_ * NH + h) * DH + d0 + dl) * S_LEN + s]) = vv;
            }
            WAIT_LGKM0(); // vt reused next mi
            __builtin_amdgcn_sched_barrier(0);
        }
    }
}

// ---------------- output projection: 8-phase counted-vmcnt, 128x128, C^T ------------
__global__ __launch_bounds__(512, 2) void gemm_o8(const unsigned short* __restrict__ Wot,
                                                  const unsigned short* __restrict__ Og,
                                                  const float* __restrict__ bo,
                                                  float* __restrict__ out) {
    __shared__ __align__(16) char lds[2][2][16384]; // [buf][A=0/B=1][128 rows x 128B]

    int t = threadIdx.x;
    int b = blockIdx.x;
    int xcd = b & 7, ii = b >> 3;       // ii in [0,32)
    int it = ii & 7;                    // all 8 i-tiles per XCD (Wot 2MB)
    int jt = (xcd << 2) | (ii >> 3);    // 4 j-tiles per XCD (Og 1MB)
    int iBase = it << 7, jBase = jt << 7;

    int w = t >> 6, lane = t & 63;
    int lr = lane & 15, lh = lane >> 4;
    int wm = w >> 2, wn = w & 3; // 2m x 4n

    int srow = t >> 3; // 0..63
    int scbx = ((t & 7) << 4) ^ ((srow & 7) << 4);

    const char* Ab = (const char*)Wot;
    const char* Bb = (const char*)Og;

    floatx4 acc[4][2];
#pragma unroll
    for (int i = 0; i < 4; i++)
#pragma unroll
        for (int j = 0; j < 2; j++) acc[i][j] = (floatx4){0.f, 0.f, 0.f, 0.f};

    auto stageA = [&](int buf, int kt) {
        int k0b = kt << 7;
#pragma unroll
        for (int c = 0; c < 2; c++)
            gl2lds16(Ab + (size_t)(iBase + c * 64 + srow) * 2048 + k0b + scbx,
                     &lds[buf][0][c * 8192 + t * 16]);
    };
    auto stageB = [&](int buf, int kt) {
        int k0b = kt << 7;
#pragma unroll
        for (int c = 0; c < 2; c++)
            gl2lds16(Bb + (size_t)(jBase + c * 64 + srow) * 2048 + k0b + scbx,
                     &lds[buf][1][c * 8192 + t * 16]);
    };

    short8 af[4][2], bf[2][2];
    auto rdA = [&](int buf, int qm) {
#pragma unroll
        for (int m2 = 0; m2 < 2; m2++)
#pragma unroll
            for (int ks = 0; ks < 2; ks++) {
                int mi = qm * 2 + m2;
                int row = wm * 64 + mi * 16 + lr;
                af[mi][ks] = *reinterpret_cast<const short8*>(
                    &lds[buf][0][(row * 128 + ks * 64 + lh * 16) ^ ((row & 7) << 4)]);
            }
    };
    auto rdB = [&](int buf) {
#pragma unroll
        for (int nf = 0; nf < 2; nf++)
#pragma unroll
            for (int ks = 0; ks < 2; ks++) {
                int row = wn * 32 + nf * 16 + lr;
                bf[nf][ks] = *reinterpret_cast<const short8*>(
                    &lds[buf][1][(row * 128 + ks * 64 + lh * 16) ^ ((row & 7) << 4)]);
            }
    };
    auto mfma8 = [&](int qm) {
        __builtin_amdgcn_s_setprio(1);
#pragma unroll
        for (int m2 = 0; m2 < 2; m2++)
#pragma unroll
            for (int nf = 0; nf < 2; nf++)
#pragma unroll
                for (int ks = 0; ks < 2; ks++) {
                    int mi = qm * 2 + m2;
                    acc[mi][nf] = __builtin_amdgcn_mfma_f32_16x16x32_bf16(
                        af[mi][ks], bf[nf][ks], acc[mi][nf], 0, 0, 0);
                }
        __builtin_amdgcn_s_setprio(0);
    };

    const int NT = 16; // K=1024 / 64
    stageA(0, 0);
    stageB(0, 0);
    WAIT_VM0();
    __builtin_amdgcn_s_barrier();

    for (int kt = 0; kt < NT; ++kt) {
        int cur = kt & 1, nxt = cur ^ 1;
        bool pf = (kt + 1 < NT);
        rdA(cur, 0);
        rdB(cur);
        if (pf) stageA(nxt, kt + 1);
        __builtin_amdgcn_s_barrier();
        WAIT_LGKM0();
        __builtin_amdgcn_sched_barrier(0);
        mfma8(0);
        __builtin_amdgcn_s_barrier();
        rdA(cur, 1);
        if (pf) stageB(nxt, kt + 1);
        __builtin_amdgcn_s_barrier();
        WAIT_LGKM0();
        __builtin_amdgcn_sched_barrier(0);
        mfma8(1);
        if (pf) WAIT_VM0();
        __builtin_amdgcn_s_barrier();
    }

#pragma unroll
    for (int mi = 0; mi < 4; mi++) {
        int i = iBase + wm * 64 + mi * 16 + lh * 4;
        float4 bs = *reinterpret_cast<const float4*>(&bo[i]);
#pragma unroll
        for (int nf = 0; nf < 2; nf++) {
            int j = jBase + wn * 32 + nf * 16 + lr;
            float4 o;
            o.x = acc[mi][nf][0] + bs.x;
            o.y = acc[mi][nf][1] + bs.y;
            o.z = acc[mi][nf][2] + bs.z;
            o.w = acc[mi][nf][3] + bs.w;
            *reinterpret_cast<float4*>(&out[(size_t)j * E_DIM + i]) = o;
        }
    }
}

// ---------------- causal flash attention: swapped QK^T, in-register P ---------------
__global__ __launch_bounds__(256, 4) void attn_fwd(const unsigned short* __restrict__ Qg,
                                                   const unsigned short* __restrict__ Kg,
                                                   const unsigned short* __restrict__ Vtg,
                                                   unsigned short* __restrict__ Og,
                                                   unsigned short* __restrict__ Opart,
                                                   float* __restrict__ lpart) {
    __shared__ __align__(16) char kt_lds[2][KVB * 128];
    __shared__ __align__(16) char vt_lds[2][KVB * 128];

    int bid = blockIdx.x;
    int xcd = bid & 7, ii = bid >> 3;  // [0,120)
    int bh = (xcd << 2) + ii / 30;
    int jj = 29 - (ii % 30);           // dispatch big-qb chunks first
    int qb, ch, c;
    if (jj < 6)        { qb = jj; ch = 0; c = 1; }
    else if (jj < 18)  { int u = jj - 6;  qb = 6 + (u >> 1); ch = u & 1; c = 2; }
    else               { int u = jj - 18; qb = 12 + u / 3;   ch = u % 3; c = 3; }
    int T = 2 * qb + 2;
    int kt_lo = ch * T / c;
    int kt_hi = (ch + 1) * T / c - 1;
    bool split = (c > 1);

    int w = threadIdx.x >> 6, lane = threadIdx.x & 63;
    int lr = lane & 15, lh = lane >> 4;
    int q0 = qb * QB + w * 32;

    const char* Kb = (const char*)(Kg + (size_t)bh * S_LEN * DH);
    const char* Vb = (const char*)(Vtg + (size_t)bh * DH * S_LEN);
    const unsigned short* Qb = Qg + (size_t)bh * S_LEN * DH;

    int wi0 = w * 2;
    int srow0 = wi0 * 8 + (lane >> 3);
    int scol = (lane & 7) << 4;

    auto stage = [&](int buf, int kt) { // K + V tiles, 2+2 x 1KB per wave
        int kv0 = kt * KVB;
#pragma unroll
        for (int i = 0; i < 2; ++i) {
            int row = srow0 + i * 8;
            int colb = scol ^ ((row & 7) << 4);
            gl2lds16(Kb + (size_t)(kv0 + row) * 128 + colb,
                     kt_lds[buf] + (wi0 + i) * 1024);
            gl2lds16(Vb + (size_t)row * (S_LEN * 2) + (size_t)kv0 * 2 + colb,
                     vt_lds[buf] + (wi0 + i) * 1024);
        }
    };

    short8 aq[2][2];
#pragma unroll
    for (int m = 0; m < 2; m++)
#pragma unroll
        for (int ks = 0; ks < 2; ks++)
            aq[m][ks] = *reinterpret_cast<const short8*>(
                Qb + (size_t)(q0 + m * 16 + lr) * DH + ks * 32 + lh * 8);

    floatx4 oacc[2][4];
    float lsum[2];
#pragma unroll
    for (int m = 0; m < 2; m++) {
#pragma unroll
        for (int dt = 0; dt < 4; dt++) oacc[m][dt] = (floatx4){0.f, 0.f, 0.f, 0.f};
        lsum[m] = 0.f;
    }

    stage(0, kt_lo);
    __syncthreads();
    int buf = 0;

    for (int kt = kt_lo; kt <= kt_hi; ++kt) {
        if (kt < kt_hi) stage(buf ^ 1, kt + 1);
        int kv0 = kt * KVB;
        bool skip = (kv0 > q0 + 31);
        if (!skip) {
            const char* Kt = kt_lds[buf];
            const char* Vt = vt_lds[buf];
            floatx4 sacc[2][4];
#pragma unroll
            for (int m = 0; m < 2; m++)
#pragma unroll
                for (int nt = 0; nt < 4; nt++) sacc[m][nt] = (floatx4){0.f, 0.f, 0.f, 0.f};
#pragma unroll
            for (int ks = 0; ks < 2; ks++)
#pragma unroll
                for (int nt = 0; nt < 4; nt++) {
                    int row = nt * 16 + lr;
                    int addr = (row * 128 + ks * 64 + lh * 16) ^ ((row & 7) << 4);
                    short8 bk = *reinterpret_cast<const short8*>(Kt + addr);
#pragma unroll
                    for (int m = 0; m < 2; m++)
                        sacc[m][nt] = __builtin_amdgcn_mfma_f32_16x16x32_bf16(
                            bk, aq[m][ks], sacc[m][nt], 0, 0, 0);
                }
            if (kv0 + KVB - 1 > q0) {
#pragma unroll
                for (int m = 0; m < 2; m++)
#pragma unroll
                    for (int nt = 0; nt < 4; nt++)
#pragma unroll
                        for (int r = 0; r < 4; r++) {
                            int kcol = kv0 + nt * 16 + lh * 4 + r;
                            int qrow = q0 + m * 16 + lr;
                            if (kcol > qrow) sacc[m][nt][r] = -1e30f;
                        }
            }
            unsigned int pk[2][4][2];
#pragma unroll
            for (int m = 0; m < 2; m++) {
                float ls = 0.f;
#pragma unroll
                for (int nt = 0; nt < 4; nt++) {
#pragma unroll
                    for (int r = 0; r < 4; r++) {
                        float p = __builtin_amdgcn_exp2f(sacc[m][nt][r]);
                        sacc[m][nt][r] = p;
                        ls += p;
                    }
                    pk[m][nt][0] = pack2bf(sacc[m][nt][0], sacc[m][nt][1]);
                    pk[m][nt][1] = pack2bf(sacc[m][nt][2], sacc[m][nt][3]);
                }
                lsum[m] += ls;
            }
            short8 pa[2][2];
            int hsel = lh >> 1;
#pragma unroll
            for (int m = 0; m < 2; m++)
#pragma unroll
                for (int ks = 0; ks < 2; ks++) {
                    intx4 u;
#pragma unroll
                    for (int t4 = 0; t4 < 4; t4++) {
                        int src = lr + 32 * (lh & 1) + 16 * (t4 >> 1);
                        int r0 = __shfl((int)pk[m][2 * ks][t4 & 1], src);
                        int r1 = __shfl((int)pk[m][2 * ks + 1][t4 & 1], src);
                        u[t4] = hsel ? r1 : r0;
                    }
                    pa[m][ks] = __builtin_bit_cast(short8, u);
                }
#pragma unroll
            for (int ks = 0; ks < 2; ks++)
#pragma unroll
                for (int dt = 0; dt < 4; dt++) {
                    int row = dt * 16 + lr;
                    int addr = (row * 128 + ks * 64 + lh * 16) ^ ((row & 7) << 4);
                    short8 bv = *reinterpret_cast<const short8*>(Vt + addr);
#pragma unroll
                    for (int m = 0; m < 2; m++)
                        oacc[m][dt] = __builtin_amdgcn_mfma_f32_16x16x32_bf16(
                            pa[m][ks], bv, oacc[m][dt], 0, 0, 0);
                }
        }
        __syncthreads();
        buf ^= 1;
    }

#pragma unroll
    for (int m = 0; m < 2; m++) {
        lsum[m] += __shfl_xor(lsum[m], 16);
        lsum[m] += __shfl_xor(lsum[m], 32);
    }

    if (split) {
        int base = (qb < 12) ? (qb - 6) * 2 : 12 + (qb - 12) * 3;
        int pi = bh * 24 + base + ch;
        unsigned short* Op = Opart + (size_t)pi * (QB * DH);
        float* lp = lpart + (size_t)pi * QB;
#pragma unroll
        for (int m = 0; m < 2; m++) {
            if (lh == 0) lp[w * 32 + m * 16 + lr] = lsum[m];
#pragma unroll
            for (int r = 0; r < 4; r++) {
                int row = w * 32 + m * 16 + lh * 4 + r;
#pragma unroll
                for (int dt = 0; dt < 4; dt++)
                    Op[row * DH + dt * 16 + lr] = f2bf(oacc[m][dt][r]);
            }
        }
    } else {
        int b_ = bh >> 4, h_ = bh & 15;
#pragma unroll
        for (int m = 0; m < 2; m++) {
#pragma unroll
            for (int r = 0; r < 4; r++) {
                float lv = __shfl(lsum[m], lh * 4 + r);
                float inv = 1.f / lv;
                int srow = q0 + m * 16 + lh * 4 + r;
#pragma unroll
                for (int dt = 0; dt < 4; dt++)
                    Og[((size_t)b_ * S_LEN + srow) * E_DIM + h_ * 64 + dt * 16 + lr] =
                        f2bf(oacc[m][dt][r] * inv);
            }
        }
    }
}

// ---------------- merge KV-split partials (2 or 3 chunks), normalize, write Og ------
__global__ __launch_bounds__(256) void attn_reduce(const unsigned short* __restrict__ Opart,
                                                   const float* __restrict__ lpart,
                                                   unsigned short* __restrict__ Og) {
    int bh = blockIdx.x;      // 0..31
    int qb = 6 + blockIdx.y;  // 6..15
    int c = (qb < 12) ? 2 : 3;
    int base = (qb < 12) ? (qb - 6) * 2 : 12 + (qb - 12) * 3;
    int pi0 = bh * 24 + base;
    const unsigned short* P0 = Opart + (size_t)pi0 * (QB * DH);
    const float* l0 = lpart + (size_t)pi0 * QB;
    int t = threadIdx.x;
    int cg = t & 7, r0 = t >> 3;
    int b_ = bh >> 4, h_ = bh & 15;
    int qrow0 = qb * QB;
#pragma unroll
    for (int rr = 0; rr < 4; rr++) {
        int row = r0 + rr * 32;
        float ls = l0[row] + l0[QB + row];
        if (c == 3) ls += l0[2 * QB + row];
        float inv = 1.f / ls;
        short8 v0 = *reinterpret_cast<const short8*>(P0 + row * DH + cg * 8);
        short8 v1 = *reinterpret_cast<const short8*>(P0 + QB * DH + row * DH + cg * 8);
        float s[8];
#pragma unroll
        for (int j = 0; j < 8; j++)
            s[j] = bf2f((unsigned short)v0[j]) + bf2f((unsigned short)v1[j]);
        if (c == 3) {
            short8 v2 = *reinterpret_cast<const short8*>(P0 + 2 * QB * DH + row * DH + cg * 8);
#pragma unroll
            for (int j = 0; j < 8; j++) s[j] += bf2f((unsigned short)v2[j]);
        }
        short8 o;
#pragma unroll
        for (int j = 0; j < 8; j++) o[j] = (short)f2bf(s[j] * inv);
        *reinterpret_cast<short8*>(Og + ((size_t)b_ * S_LEN + qrow0 + row) * E_DIM +
                                   h_ * 64 + cg * 8) = o;
    }
}

extern "C" void kernel_launch(void* const* d_in, const int* in_sizes, int n_in,
                              void* d_out, int out_size, void* d_ws, size_t ws_size,
                              hipStream_t stream) {
    const float* x  = (const float*)d_in[0];
    const float* Wq = (const float*)d_in[1];
    const float* bq = (const float*)d_in[2];
    const float* Wk = (const float*)d_in[3];
    const float* bk = (const float*)d_in[4];
    const float* Wv = (const float*)d_in[5];
    const float* bv = (const float*)d_in[6];
    const float* Wo = (const float*)d_in[7];
    const float* bo = (const float*)d_in[8];
    float* out = (float*)d_out;

    const size_t NX = (size_t)M_ROWS * E_DIM; // 4M elems
    const size_t NW = (size_t)E_DIM * E_DIM;  // 1M elems
    unsigned short* ws  = (unsigned short*)d_ws;
    unsigned short* Xb  = ws;
    unsigned short* Wqt = Xb + NX;   // Wqt|Wkt|Wvt contiguous = Wcat [3072][1024]
    unsigned short* Wkt = Wqt + NW;
    unsigned short* Wvt = Wkt + NW;
    unsigned short* Wot = Wvt + NW;
    unsigned short* Qg  = Wot + NW;
    unsigned short* Kg  = Qg + NX;
    unsigned short* Vtg = Kg + NX;
    unsigned short* Og  = Vtg + NX;
    // Partials OVERLAY the Xb/Wqt/Wkt/Wvt region (dead after gemm_qkv8):
    unsigned short* Opart = Xb;
    float* lpart = (float*)(Opart + (size_t)32 * 24 * QB * DH);

    prep<<<dim3(8192), 256, 0, stream>>>(x, Xb, Wq, Wk, Wv, Wo, Wqt, Wkt, Wvt, Wot);

    gemm_qkv8<<<dim3(256), 512, 0, stream>>>(Wqt, Xb, bq, bk, bv, Qg, Kg, Vtg);

    attn_fwd<<<dim3(960), 256, 0, stream>>>(Qg, Kg, Vtg, Og, Opart, lpart);
    attn_reduce<<<dim3(B_SZ * NH, 10), 256, 0, stream>>>(Opart, lpart, Og);

    gemm_o8<<<dim3(256), 512, 0, stream>>>(Wot, Og, bo, out);
}